// Round 7
// baseline (1273.592 us; speedup 1.0000x reference)
//
#include <hip/hip_runtime.h>
#include <math.h>

#define N_NODES 50000
#define N_EDGES 800000
#define N_GRAPH 2000
#define F_INPUT 34
#define HID 256
#define NLAYER 5

typedef __attribute__((ext_vector_type(8))) short short8;
typedef __attribute__((ext_vector_type(4))) float float4v;

// ---------- helpers ----------
__device__ __forceinline__ float gelu_f(float x) {
  return 0.5f * x * (1.0f + erff(x * 0.70710678118654752440f));
}
__device__ __forceinline__ unsigned short bfr(float f) {  // fp32 -> bf16 RNE
  unsigned u = __float_as_uint(f);
  return (unsigned short)((u + 0x7fffu + ((u >> 16) & 1u)) >> 16);
}
__device__ __forceinline__ float b2f(unsigned short s) {
  return __uint_as_float(((unsigned)s) << 16);
}
__device__ __forceinline__ float4 ld4bf(const unsigned short* p) {
  ushort4 u = *(const ushort4*)p;
  float4 f;
  f.x = b2f(u.x); f.y = b2f(u.y); f.z = b2f(u.z); f.w = b2f(u.w);
  return f;
}
// async global->LDS, 16B per lane; lds dest = wave-uniform base + lane*16
__device__ __forceinline__ void acp16(const unsigned short* g, unsigned short* l) {
  __builtin_amdgcn_global_load_lds(
      (const __attribute__((address_space(1))) void*)g,
      (__attribute__((address_space(3))) void*)l, 16, 0, 0);
}

// ---------- fp32 GEMM (input embed K=34 only) ----------
__global__ __launch_bounds__(256) void gemm_bias(
    const float* __restrict__ A, const float* __restrict__ B,
    const float* __restrict__ bias, float* __restrict__ C,
    int M, int Nn, int K) {
  __shared__ float As[16][64];
  __shared__ float Bs[16][64];
  int tid = threadIdx.x;
  int tx = tid & 15, ty = tid >> 4;
  int row0 = blockIdx.y * 64;
  int col0 = blockIdx.x * 64;
  float acc[4][4] = {};
  int a_r = tid >> 2;
  int a_c = (tid & 3) * 4;
  int b_r = tid >> 4;
  int b_c = (tid & 15) * 4;

  for (int k0 = 0; k0 < K; k0 += 16) {
    int ar = row0 + a_r;
#pragma unroll
    for (int i = 0; i < 4; ++i) {
      int kc = k0 + a_c + i;
      As[a_c + i][a_r] = (ar < M && kc < K) ? A[(long)ar * K + kc] : 0.f;
    }
    int bk = k0 + b_r;
    if (bk < K) {
      float4 bv = *(const float4*)&B[(long)bk * Nn + col0 + b_c];
      Bs[b_r][b_c + 0] = bv.x; Bs[b_r][b_c + 1] = bv.y;
      Bs[b_r][b_c + 2] = bv.z; Bs[b_r][b_c + 3] = bv.w;
    } else {
      Bs[b_r][b_c + 0] = 0.f; Bs[b_r][b_c + 1] = 0.f;
      Bs[b_r][b_c + 2] = 0.f; Bs[b_r][b_c + 3] = 0.f;
    }
    __syncthreads();
#pragma unroll
    for (int kk = 0; kk < 16; ++kk) {
      float4 a = *(const float4*)&As[kk][ty * 4];
      float4 b = *(const float4*)&Bs[kk][tx * 4];
      float av[4] = {a.x, a.y, a.z, a.w};
      float bv[4] = {b.x, b.y, b.z, b.w};
#pragma unroll
      for (int i = 0; i < 4; ++i)
#pragma unroll
        for (int j = 0; j < 4; ++j) acc[i][j] += av[i] * bv[j];
    }
    __syncthreads();
  }
  float4 bi = *(const float4*)&bias[col0 + tx * 4];
  float bia[4] = {bi.x, bi.y, bi.z, bi.w};
#pragma unroll
  for (int i = 0; i < 4; ++i) {
    int r = row0 + ty * 4 + i;
    if (r < M) {
      float4 o;
      o.x = acc[i][0] + bia[0]; o.y = acc[i][1] + bia[1];
      o.z = acc[i][2] + bia[2]; o.w = acc[i][3] + bia[3];
      *(float4*)&C[(long)r * Nn + col0 + tx * 4] = o;
    }
  }
}

// ---------- bf16 MFMA GEMM (m97-style async LDS staging) ----------
__global__ __launch_bounds__(256) void gemm_mfma(
    const unsigned short* __restrict__ A, const unsigned short* __restrict__ Bt,
    const float* __restrict__ bias, void* __restrict__ Cv,
    int M, int Nn, int K, int flags) {
  __shared__ unsigned short smem[12288];  // As[128][32]@0, Bs@4096; epilogue overlay
  unsigned short* As = smem;
  unsigned short* Bs = smem + 4096;
  int tid = threadIdx.x;
  int wave = tid >> 6, lane = tid & 63;
  int row0 = blockIdx.y * 128;
  int col0 = blockIdx.x * 128;
  int wm0 = (wave >> 1) * 64;
  int wn0 = (wave & 1) * 64;
  int q = lane >> 4;
  int ln = lane & 15;

  int srow = wave * 16 + (lane >> 2);
  int scol = (lane & 3) * 8;
  int ra0 = min(row0 + srow, M - 1);
  int ra1 = min(row0 + srow + 64, M - 1);
  const unsigned short* pa0 = A + (size_t)ra0 * K + scol;
  const unsigned short* pa1 = A + (size_t)ra1 * K + scol;
  const unsigned short* pb0 = Bt + (size_t)(col0 + srow) * K + scol;
  const unsigned short* pb1 = Bt + (size_t)(col0 + srow + 64) * K + scol;
  unsigned short* la0 = As + wave * 512;
  unsigned short* la1 = As + wave * 512 + 2048;
  unsigned short* lb0 = Bs + wave * 512;
  unsigned short* lb1 = Bs + wave * 512 + 2048;

  float4v acc[4][4];
#pragma unroll
  for (int i = 0; i < 4; ++i)
#pragma unroll
    for (int j = 0; j < 4; ++j) acc[i][j] = (float4v)0.f;

  for (int k0 = 0; k0 < K; k0 += 32) {
    acp16(pa0 + k0, la0);
    acp16(pa1 + k0, la1);
    acp16(pb0 + k0, lb0);
    acp16(pb1 + k0, lb1);
    __syncthreads();
    short8 af[4], bf[4];
#pragma unroll
    for (int i = 0; i < 4; ++i)
      af[i] = *(const short8*)&As[(wm0 + i * 16 + ln) * 32 + q * 8];
#pragma unroll
    for (int j = 0; j < 4; ++j)
      bf[j] = *(const short8*)&Bs[(wn0 + j * 16 + ln) * 32 + q * 8];
#pragma unroll
    for (int i = 0; i < 4; ++i)
#pragma unroll
      for (int j = 0; j < 4; ++j)
        acc[i][j] = __builtin_amdgcn_mfma_f32_16x16x32_bf16(af[i], bf[j], acc[i][j], 0, 0, 0);
    __syncthreads();
  }
  int rb = (lane >> 4) * 4;
  if (flags & 2) {
    unsigned short* Cb = (unsigned short*)Cv;
    unsigned short* eb = smem + wave * 2560;  // 64 rows x stride 40
#pragma unroll
    for (int p = 0; p < 2; ++p) {
#pragma unroll
      for (int jj = 0; jj < 2; ++jj) {
        int j = p * 2 + jj;
        float bv = bias[col0 + wn0 + j * 16 + ln];
#pragma unroll
        for (int i = 0; i < 4; ++i)
#pragma unroll
          for (int r = 0; r < 4; ++r)
            eb[(i * 16 + rb + r) * 40 + jj * 16 + ln] = bfr(acc[i][j][r] + bv);
      }
      int grow = row0 + wm0 + lane;
      uint4 w0 = *(uint4*)&eb[lane * 40 + 0];
      uint4 w1 = *(uint4*)&eb[lane * 40 + 8];
      uint4 w2 = *(uint4*)&eb[lane * 40 + 16];
      uint4 w3 = *(uint4*)&eb[lane * 40 + 24];
      if (grow < M) {
        unsigned short* dst = Cb + (size_t)grow * Nn + col0 + wn0 + p * 32;
        *(uint4*)&dst[0] = w0;
        *(uint4*)&dst[8] = w1;
        *(uint4*)&dst[16] = w2;
        *(uint4*)&dst[24] = w3;
      }
    }
  } else {
    float* C = (float*)Cv;
#pragma unroll
    for (int j = 0; j < 4; ++j) {
      int col = col0 + wn0 + j * 16 + ln;
      float bv = bias[col];
#pragma unroll
      for (int i = 0; i < 4; ++i)
#pragma unroll
        for (int r = 0; r < 4; ++r) {
          int row = row0 + wm0 + i * 16 + rb + r;
          if (row < M) C[(size_t)row * Nn + col] = acc[i][j][r] + bv;
        }
    }
  }
}

// ---------- weight prep ----------
__global__ __launch_bounds__(256) void prep_w(
    const float* __restrict__ Wl, const float* __restrict__ Wr,
    const float* __restrict__ Wq, const float* __restrict__ Wk,
    const float* __restrict__ Wv, const float* __restrict__ Wsk,
    unsigned short* __restrict__ out) {
  __shared__ float t[32][33];
  int m = blockIdx.z;
  const float* W = (m < 10) ? (((m & 1) ? Wr : Wl) + (size_t)(m >> 1) * 65536)
                 : (m == 10) ? Wq : (m == 11) ? Wk : (m == 12) ? Wv : Wsk;
  int k0 = blockIdx.y * 32, n0 = blockIdx.x * 32;
  int r = threadIdx.x >> 5, c = threadIdx.x & 31;
  for (int rr = r; rr < 32; rr += 8)
    t[rr][c] = W[(size_t)(k0 + rr) * HID + n0 + c];
  __syncthreads();
  unsigned short* o = out + (size_t)m * 65536;
  for (int rr = r; rr < 32; rr += 8)
    o[(size_t)(n0 + rr) * HID + k0 + c] = bfr(t[c][rr]);
}

__global__ __launch_bounds__(256) void prep_wout(const float* __restrict__ W,
                                                 unsigned short* __restrict__ o) {
  __shared__ float t[32][33];
  int k0 = blockIdx.y * 32, n0 = blockIdx.x * 32;
  int r = threadIdx.x >> 5, c = threadIdx.x & 31;
  for (int rr = r; rr < 32; rr += 8)
    t[rr][c] = W[(size_t)(k0 + rr) * 512 + n0 + c];
  __syncthreads();
  for (int rr = r; rr < 32; rr += 8)
    o[(size_t)(n0 + rr) * 512 + k0 + c] = bfr(t[c][rr]);
}

__global__ __launch_bounds__(256) void prep_bias(
    const float* __restrict__ bl, const float* __restrict__ br,
    const float* __restrict__ bq, const float* __restrict__ bk,
    const float* __restrict__ bv, float* __restrict__ out) {
  int i = blockIdx.x * 256 + threadIdx.x;
  if (i < 2560) {
    int l = i >> 9, c = i & 511;
    out[i] = (c < 256) ? bl[l * 256 + c] : br[l * 256 + (c - 256)];
  } else if (i < 3328) {
    int j = i - 2560;
    out[i] = (j < 256) ? bq[j] : (j < 512) ? bk[j - 256] : bv[j - 512];
  }
}

// ---------- LayerNorm standalone (embed + final out) ----------
__global__ __launch_bounds__(256) void ln_act(
    const float* __restrict__ in, const float* __restrict__ gam,
    const float* __restrict__ bet, float* __restrict__ out,
    unsigned short* __restrict__ outb,
    int n_rows, int width, int do_gelu) {
  int wid = blockIdx.x * 4 + (threadIdx.x >> 6);
  int lane = threadIdx.x & 63;
  if (wid >= n_rows) return;
  int chunks = width >> 8;
  float4 v[2];
  float s = 0.f;
  for (int c = 0; c < chunks; ++c) {
    int off = c * 256 + lane * 4;
    float4 t = *(const float4*)&in[(size_t)wid * width + off];
    v[c] = t;
    s += t.x + t.y + t.z + t.w;
  }
  for (int o = 1; o < 64; o <<= 1) s += __shfl_xor(s, o);
  float mean = s / (float)width;
  float vs = 0.f;
  for (int c = 0; c < chunks; ++c) {
    float dx = v[c].x - mean, dy = v[c].y - mean, dz = v[c].z - mean, dw = v[c].w - mean;
    vs += dx * dx + dy * dy + dz * dz + dw * dw;
  }
  for (int o = 1; o < 64; o <<= 1) vs += __shfl_xor(vs, o);
  float inv = rsqrtf(vs / (float)width + 1e-5f);
  for (int c = 0; c < chunks; ++c) {
    int off = c * 256 + lane * 4;
    float4 g4 = *(const float4*)&gam[off];
    float4 b4 = *(const float4*)&bet[off];
    float y[4] = {(v[c].x - mean) * inv * g4.x + b4.x,
                  (v[c].y - mean) * inv * g4.y + b4.y,
                  (v[c].z - mean) * inv * g4.z + b4.z,
                  (v[c].w - mean) * inv * g4.w + b4.w};
    if (do_gelu) {
#pragma unroll
      for (int i = 0; i < 4; ++i) y[i] = gelu_f(y[i]);
    }
    size_t idx = (size_t)wid * width + off;
    float4 o4 = {y[0], y[1], y[2], y[3]};
    *(float4*)&out[idx] = o4;
    if (outb) {
      ushort4 ob = {bfr(y[0]), bfr(y[1]), bfr(y[2]), bfr(y[3])};
      *(ushort4*)&outb[idx] = ob;
    }
  }
}

// ---------- CSR build (two-level scan) ----------
__global__ __launch_bounds__(256) void edge_count(const int* __restrict__ ei,
                                                  int* __restrict__ counts) {
  int e = blockIdx.x * 256 + threadIdx.x;
  if (e < N_EDGES) atomicAdd(&counts[ei[N_EDGES + e]], 1);
}

__global__ __launch_bounds__(1024) void scan1(const int* __restrict__ counts,
                                              int* __restrict__ indptr,
                                              int* __restrict__ bsums, int n) {
  __shared__ int sm[1024];
  int tid = threadIdx.x;
  int i = blockIdx.x * 1024 + tid;
  int v = (i < n) ? counts[i] : 0;
  sm[tid] = v;
  __syncthreads();
  for (int off = 1; off < 1024; off <<= 1) {
    int t = (tid >= off) ? sm[tid - off] : 0;
    __syncthreads();
    sm[tid] += t;
    __syncthreads();
  }
  if (i < n) indptr[i] = sm[tid] - v;
  if (tid == 1023) bsums[blockIdx.x] = sm[1023];
}

__global__ void scan2(int* __restrict__ bsums, int nb) {
  if (threadIdx.x == 0 && blockIdx.x == 0) {
    int acc = 0;
    for (int i = 0; i < nb; ++i) { int t = bsums[i]; bsums[i] = acc; acc += t; }
  }
}

__global__ __launch_bounds__(256) void scan3(const int* __restrict__ bsums,
                                             int* __restrict__ indptr,
                                             int* __restrict__ cursor, int n) {
  int i = blockIdx.x * 256 + threadIdx.x;
  if (i < n) {
    int v = indptr[i] + bsums[i >> 10];
    indptr[i] = v;
    cursor[i] = v;
  }
  if (i == 0) indptr[n] = N_EDGES;
}

__global__ __launch_bounds__(256) void edge_scatter(const int* __restrict__ ei,
                                                    int* __restrict__ cursor,
                                                    int* __restrict__ esrc) {
  int e = blockIdx.x * 256 + threadIdx.x;
  if (e < N_EDGES) {
    int d = ei[N_EDGES + e];
    int p = atomicAdd(&cursor[d], 1);
    esrc[p] = ei[e];
  }
}

// ---------- GATv2 agg + bias + LN + GELU + residual (fused, branchless) ----------
#define GAT_EDGE(f)                                                        \
  {                                                                        \
    float ex = f.x + xri.x; ex = ex > 0.f ? ex : 0.2f * ex;                \
    float ey = f.y + xri.y; ey = ey > 0.f ? ey : 0.2f * ey;                \
    float ez = f.z + xri.z; ez = ez > 0.f ? ez : 0.2f * ez;                \
    float ew = f.w + xri.w; ew = ew > 0.f ? ew : 0.2f * ew;                \
    float p = ex * a4.x + ey * a4.y + ez * a4.z + ew * a4.w;               \
    p += __shfl_xor(p, 1); p += __shfl_xor(p, 2); p += __shfl_xor(p, 4);   \
    float wgt = __expf(fminf(p - m0, 60.f));                               \
    ax += wgt * f.x; ay += wgt * f.y; az += wgt * f.z; aw += wgt * f.w;    \
    lsum += wgt;                                                           \
  }

__global__ __launch_bounds__(256) void gat_agg(
    const unsigned short* __restrict__ xlr, const float* __restrict__ att,
    const int* __restrict__ indptr, const int* __restrict__ esrc,
    const float* __restrict__ pre_bias, const float* __restrict__ gam,
    const float* __restrict__ bet, float* __restrict__ h,
    unsigned short* __restrict__ hb) {
  int wid = blockIdx.x * 4 + (threadIdx.x >> 6);
  int lane = threadIdx.x & 63;
  if (wid >= N_NODES) return;
  size_t idx = (size_t)wid * HID + lane * 4;
  // hoisted epilogue operands (overlap with gather latency)
  float4 pb = *(const float4*)&pre_bias[lane * 4];
  float4 g4 = *(const float4*)&gam[lane * 4];
  float4 b4 = *(const float4*)&bet[lane * 4];
  float4 r4 = *(const float4*)&h[idx];
  float4 xri = ld4bf(&xlr[(size_t)wid * 512 + 256 + lane * 4]);
  float4 a4 = *(const float4*)&att[lane * 4];
  int beg = indptr[wid], end = indptr[wid + 1];

  float m0, lsum, ax, ay, az, aw;
  {  // self loop = softmax anchor
    float4 f = ld4bf(&xlr[(size_t)wid * 512 + lane * 4]);
    float ex = f.x + xri.x; ex = ex > 0.f ? ex : 0.2f * ex;
    float ey = f.y + xri.y; ey = ey > 0.f ? ey : 0.2f * ey;
    float ez = f.z + xri.z; ez = ez > 0.f ? ez : 0.2f * ez;
    float ew = f.w + xri.w; ew = ew > 0.f ? ew : 0.2f * ew;
    float p = ex * a4.x + ey * a4.y + ez * a4.z + ew * a4.w;
    p += __shfl_xor(p, 1); p += __shfl_xor(p, 2); p += __shfl_xor(p, 4);
    m0 = p; lsum = 1.f;
    ax = f.x; ay = f.y; az = f.z; aw = f.w;
  }
  int e = beg;
  for (; e + 7 < end; e += 8) {  // 8 gathers in flight
    int j0 = esrc[e],     j1 = esrc[e + 1], j2 = esrc[e + 2], j3 = esrc[e + 3];
    int j4 = esrc[e + 4], j5 = esrc[e + 5], j6 = esrc[e + 6], j7 = esrc[e + 7];
    float4 f0 = ld4bf(&xlr[(size_t)j0 * 512 + lane * 4]);
    float4 f1 = ld4bf(&xlr[(size_t)j1 * 512 + lane * 4]);
    float4 f2 = ld4bf(&xlr[(size_t)j2 * 512 + lane * 4]);
    float4 f3 = ld4bf(&xlr[(size_t)j3 * 512 + lane * 4]);
    float4 f4 = ld4bf(&xlr[(size_t)j4 * 512 + lane * 4]);
    float4 f5 = ld4bf(&xlr[(size_t)j5 * 512 + lane * 4]);
    float4 f6 = ld4bf(&xlr[(size_t)j6 * 512 + lane * 4]);
    float4 f7 = ld4bf(&xlr[(size_t)j7 * 512 + lane * 4]);
    GAT_EDGE(f0); GAT_EDGE(f1); GAT_EDGE(f2); GAT_EDGE(f3);
    GAT_EDGE(f4); GAT_EDGE(f5); GAT_EDGE(f6); GAT_EDGE(f7);
  }
  for (; e + 3 < end; e += 4) {
    int j0 = esrc[e], j1 = esrc[e + 1], j2 = esrc[e + 2], j3 = esrc[e + 3];
    float4 f0 = ld4bf(&xlr[(size_t)j0 * 512 + lane * 4]);
    float4 f1 = ld4bf(&xlr[(size_t)j1 * 512 + lane * 4]);
    float4 f2 = ld4bf(&xlr[(size_t)j2 * 512 + lane * 4]);
    float4 f3 = ld4bf(&xlr[(size_t)j3 * 512 + lane * 4]);
    GAT_EDGE(f0); GAT_EDGE(f1); GAT_EDGE(f2); GAT_EDGE(f3);
  }
  for (; e < end; ++e) {
    int j = esrc[e];
    float4 f = ld4bf(&xlr[(size_t)j * 512 + lane * 4]);
    GAT_EDGE(f);
  }
  float inv = 1.f / (lsum + 1e-16f);
  float y0 = ax * inv + pb.x, y1 = ay * inv + pb.y;
  float y2 = az * inv + pb.z, y3 = aw * inv + pb.w;
  float s = y0 + y1 + y2 + y3;
  for (int o = 1; o < 64; o <<= 1) s += __shfl_xor(s, o);
  float mean = s * (1.f / 256.f);
  float d0 = y0 - mean, d1 = y1 - mean, d2 = y2 - mean, d3 = y3 - mean;
  float vs = d0 * d0 + d1 * d1 + d2 * d2 + d3 * d3;
  for (int o = 1; o < 64; o <<= 1) vs += __shfl_xor(vs, o);
  float inv2 = rsqrtf(vs * (1.f / 256.f) + 1e-5f);
  y0 = gelu_f(d0 * inv2 * g4.x + b4.x) + r4.x;
  y1 = gelu_f(d1 * inv2 * g4.y + b4.y) + r4.y;
  y2 = gelu_f(d2 * inv2 * g4.z + b4.z) + r4.z;
  y3 = gelu_f(d3 * inv2 * g4.w + b4.w) + r4.w;
  float4 o4 = {y0, y1, y2, y3};
  *(float4*)&h[idx] = o4;
  ushort4 ob = {bfr(y0), bfr(y1), bfr(y2), bfr(y3)};
  *(ushort4*)&hb[idx] = ob;
}

// ---------- TransformerConv agg + skip + LN + residual (fused, branchless) ----------
#define TR_EDGE(kj, vj)                                                    \
  {                                                                        \
    float p = qi.x * kj.x + qi.y * kj.y + qi.z * kj.z + qi.w * kj.w;       \
    p += __shfl_xor(p, 1); p += __shfl_xor(p, 2); p += __shfl_xor(p, 4);   \
    float wgt = __expf(fminf(p * scale, 60.f));                            \
    ax += wgt * vj.x; ay += wgt * vj.y; az += wgt * vj.z; aw += wgt * vj.w;\
    lsum += wgt;                                                           \
  }

__global__ __launch_bounds__(256) void tr_agg(
    const unsigned short* __restrict__ qkv, const int* __restrict__ indptr,
    const int* __restrict__ esrc, const unsigned short* __restrict__ skipb,
    const float* __restrict__ gam, const float* __restrict__ bet,
    float* __restrict__ h) {
  int wid = blockIdx.x * 4 + (threadIdx.x >> 6);
  int lane = threadIdx.x & 63;
  if (wid >= N_NODES) return;
  size_t idx = (size_t)wid * HID + lane * 4;
  // hoisted epilogue operands
  float4 sk = ld4bf(&skipb[idx]);
  float4 g4 = *(const float4*)&gam[lane * 4];
  float4 b4 = *(const float4*)&bet[lane * 4];
  float4 r4 = *(const float4*)&h[idx];
  float4 qi = ld4bf(&qkv[(size_t)wid * 768 + lane * 4]);
  int beg = indptr[wid], end = indptr[wid + 1];
  float lsum = 0.f;
  float ax = 0.f, ay = 0.f, az = 0.f, aw = 0.f;
  const float scale = 0.17677669529663687f;
  int e = beg;
  for (; e + 3 < end; e += 4) {  // 8 gathers in flight
    int j0 = esrc[e], j1 = esrc[e + 1], j2 = esrc[e + 2], j3 = esrc[e + 3];
    float4 k0 = ld4bf(&qkv[(size_t)j0 * 768 + 256 + lane * 4]);
    float4 v0 = ld4bf(&qkv[(size_t)j0 * 768 + 512 + lane * 4]);
    float4 k1 = ld4bf(&qkv[(size_t)j1 * 768 + 256 + lane * 4]);
    float4 v1 = ld4bf(&qkv[(size_t)j1 * 768 + 512 + lane * 4]);
    float4 k2 = ld4bf(&qkv[(size_t)j2 * 768 + 256 + lane * 4]);
    float4 v2 = ld4bf(&qkv[(size_t)j2 * 768 + 512 + lane * 4]);
    float4 k3 = ld4bf(&qkv[(size_t)j3 * 768 + 256 + lane * 4]);
    float4 v3 = ld4bf(&qkv[(size_t)j3 * 768 + 512 + lane * 4]);
    TR_EDGE(k0, v0); TR_EDGE(k1, v1); TR_EDGE(k2, v2); TR_EDGE(k3, v3);
  }
  for (; e < end; ++e) {
    int j = esrc[e];
    float4 kj = ld4bf(&qkv[(size_t)j * 768 + 256 + lane * 4]);
    float4 vj = ld4bf(&qkv[(size_t)j * 768 + 512 + lane * 4]);
    TR_EDGE(kj, vj);
  }
  float inv = 1.f / (lsum + 1e-16f);
  float y0 = ax * inv + sk.x, y1 = ay * inv + sk.y;
  float y2 = az * inv + sk.z, y3 = aw * inv + sk.w;
  float s = y0 + y1 + y2 + y3;
  for (int o = 1; o < 64; o <<= 1) s += __shfl_xor(s, o);
  float mean = s * (1.f / 256.f);
  float d0 = y0 - mean, d1 = y1 - mean, d2 = y2 - mean, d3 = y3 - mean;
  float vs = d0 * d0 + d1 * d1 + d2 * d2 + d3 * d3;
  for (int o = 1; o < 64; o <<= 1) vs += __shfl_xor(vs, o);
  float inv2 = rsqrtf(vs * (1.f / 256.f) + 1e-5f);
  float4 o4;
  o4.x = r4.x + d0 * inv2 * g4.x + b4.x;
  o4.y = r4.y + d1 * inv2 * g4.y + b4.y;
  o4.z = r4.z + d2 * inv2 * g4.z + b4.z;
  o4.w = r4.w + d3 * inv2 * g4.w + b4.w;
  *(float4*)&h[idx] = o4;
}

// ---------- pooling over sorted batch ----------
__global__ __launch_bounds__(256) void graph_bounds(const int* __restrict__ batch,
                                                    int* __restrict__ gptr) {
  int i = blockIdx.x * 256 + threadIdx.x;
  if (i >= N_NODES) return;
  int b0 = batch[i];
  if (i == 0)
    for (int g = 0; g <= b0; ++g) gptr[g] = 0;
  int b1 = (i + 1 < N_NODES) ? batch[i + 1] : N_GRAPH;
  for (int g = b0 + 1; g <= b1; ++g) gptr[g] = i + 1;
}

__global__ __launch_bounds__(256) void pool_seg(
    const float* __restrict__ h, const int* __restrict__ gptr,
    unsigned short* __restrict__ geb) {
  int g = blockIdx.x, c = threadIdx.x;
  int s = gptr[g], e = gptr[g + 1];
  float sum = 0.f, mx = -INFINITY;
  for (int r = s; r < e; ++r) {
    float vv = h[(size_t)r * HID + c];
    sum += vv;
    mx = fmaxf(mx, vv);
  }
  int cnt = e - s;
  geb[(size_t)g * 512 + c] = bfr(sum / (float)max(cnt, 1));
  geb[(size_t)g * 512 + 256 + c] = bfr(cnt ? mx : 0.f);
}

// ---------- host ----------
static inline void mfma_launch(const unsigned short* A, const unsigned short* Bt,
                               const float* bias, void* C, int M, int Nn, int K,
                               int flags, hipStream_t s) {
  dim3 grid(Nn / 128, (M + 127) / 128);
  gemm_mfma<<<grid, 256, 0, s>>>(A, Bt, bias, C, M, Nn, K, flags);
}

extern "C" void kernel_launch(void* const* d_in, const int* in_sizes, int n_in,
                              void* d_out, int out_size, void* d_ws, size_t ws_size,
                              hipStream_t stream) {
  const float* x       = (const float*)d_in[0];
  const int*   ei      = (const int*)d_in[1];
  const int*   batch   = (const int*)d_in[2];
  const float* in_W    = (const float*)d_in[3];
  const float* in_b    = (const float*)d_in[4];
  const float* in_ln_g = (const float*)d_in[5];
  const float* in_ln_b = (const float*)d_in[6];
  const float* gat_Wl  = (const float*)d_in[7];
  const float* gat_bl  = (const float*)d_in[8];
  const float* gat_Wr  = (const float*)d_in[9];
  const float* gat_br  = (const float*)d_in[10];
  const float* gat_att = (const float*)d_in[11];
  const float* gat_bias= (const float*)d_in[12];
  const float* gat_ln_g= (const float*)d_in[13];
  const float* gat_ln_b= (const float*)d_in[14];
  const float* tr_Wq   = (const float*)d_in[15];
  const float* tr_bq   = (const float*)d_in[16];
  const float* tr_Wk   = (const float*)d_in[17];
  const float* tr_bk   = (const float*)d_in[18];
  const float* tr_Wv   = (const float*)d_in[19];
  const float* tr_bv   = (const float*)d_in[20];
  const float* tr_Wsk  = (const float*)d_in[21];
  const float* tr_bsk  = (const float*)d_in[22];
  const float* tr_ln_g = (const float*)d_in[23];
  const float* tr_ln_b = (const float*)d_in[24];
  const float* out_W   = (const float*)d_in[25];
  const float* out_b   = (const float*)d_in[26];
  const float* out_ln_g= (const float*)d_in[27];
  const float* out_ln_b= (const float*)d_in[28];

  // ---- workspace (256B-aligned) ----
  char* w = (char*)d_ws;
  auto take = [&](size_t bytes) -> char* {
    char* p = w;
    w += (bytes + 255) & ~(size_t)255;
    return p;
  };
  const size_t NB = (size_t)N_NODES * HID * sizeof(float);
  float* h    = (float*)take(NB);
  float* aggO = (float*)take(NB);
  unsigned short* hb  = (unsigned short*)take((size_t)N_NODES * HID * 2);
  unsigned short* xq  = (unsigned short*)take((size_t)N_NODES * 768 * 2);
  unsigned short* wbuf= (unsigned short*)take((size_t)(14 * 65536 + 262144) * 2);
  float* bcat = (float*)take(3328 * sizeof(float));
  int* indptr = (int*)take((N_NODES + 1) * sizeof(int));
  int* cursor = (int*)take(N_NODES * sizeof(int));
  int* counts = (int*)take(N_NODES * sizeof(int));
  int* esrc   = (int*)take(N_EDGES * sizeof(int));
  int* bsums  = (int*)take(64 * sizeof(int));
  unsigned short* skipb = (unsigned short*)aggO;
  char* w2 = (char*)xq;
  auto take2 = [&](size_t bytes) -> char* {
    char* p = w2;
    w2 += (bytes + 255) & ~(size_t)255;
    return p;
  };
  int* gptr = (int*)take2((N_GRAPH + 1) * sizeof(int));
  unsigned short* geb = (unsigned short*)take2((size_t)N_GRAPH * 512 * 2);
  float* tbuf = (float*)take2((size_t)N_GRAPH * 512 * sizeof(float));

  const int EB = (N_EDGES + 255) / 256;
  const int WB = (N_NODES + 3) / 4;
  const int NSB = (N_NODES + 1023) / 1024;

  // --- weight/bias prep ---
  {
    dim3 g(8, 8, 14);
    prep_w<<<g, 256, 0, stream>>>(gat_Wl, gat_Wr, tr_Wq, tr_Wk, tr_Wv, tr_Wsk, wbuf);
    dim3 g2(16, 16);
    prep_wout<<<g2, 256, 0, stream>>>(out_W, wbuf + (size_t)14 * 65536);
    prep_bias<<<13, 256, 0, stream>>>(gat_bl, gat_br, tr_bq, tr_bk, tr_bv, bcat);
  }

  // --- CSR (dst-sorted), two-level scan ---
  hipMemsetAsync(counts, 0, N_NODES * sizeof(int), stream);
  edge_count<<<EB, 256, 0, stream>>>(ei, counts);
  scan1<<<NSB, 1024, 0, stream>>>(counts, indptr, bsums, N_NODES);
  scan2<<<1, 64, 0, stream>>>(bsums, NSB);
  scan3<<<(N_NODES + 255) / 256, 256, 0, stream>>>(bsums, indptr, cursor, N_NODES);
  edge_scatter<<<EB, 256, 0, stream>>>(ei, cursor, esrc);

  // --- input embed ---
  {
    dim3 grid(HID / 64, (N_NODES + 63) / 64);
    gemm_bias<<<grid, 256, 0, stream>>>(x, in_W, in_b, aggO, N_NODES, HID, F_INPUT);
  }
  ln_act<<<WB, 256, 0, stream>>>(aggO, in_ln_g, in_ln_b, h, hb, N_NODES, HID, 1);

  // --- 5 GATv2 layers ---
  for (int l = 0; l < NLAYER; ++l) {
    mfma_launch(hb, wbuf + (size_t)(2 * l) * 65536, bcat + l * 512, xq,
                N_NODES, 512, HID, 2, stream);
    gat_agg<<<WB, 256, 0, stream>>>(xq, gat_att + l * HID, indptr, esrc,
                                    gat_bias + l * HID, gat_ln_g + l * HID,
                                    gat_ln_b + l * HID, h, hb);
  }

  // --- TransformerConv ---
  mfma_launch(hb, wbuf + (size_t)13 * 65536, tr_bsk, skipb,
              N_NODES, HID, HID, 2, stream);
  mfma_launch(hb, wbuf + (size_t)10 * 65536, bcat + 2560, xq,
              N_NODES, 768, HID, 2, stream);
  tr_agg<<<WB, 256, 0, stream>>>(xq, indptr, esrc, skipb, tr_ln_g, tr_ln_b, h);

  // --- pooling -> geb bf16 ---
  graph_bounds<<<(N_NODES + 255) / 256, 256, 0, stream>>>(batch, gptr);
  pool_seg<<<N_GRAPH, 256, 0, stream>>>(h, gptr, geb);

  // --- output proj (MFMA) + final LN/GELU ---
  mfma_launch(geb, wbuf + (size_t)14 * 65536, out_b, tbuf,
              N_GRAPH, 512, 512, 0, stream);
  ln_act<<<(N_GRAPH + 3) / 4, 256, 0, stream>>>(tbuf, out_ln_g, out_ln_b,
                                                (float*)d_out, nullptr,
                                                N_GRAPH, 512, 1);
}

// Round 8
// 1205.223 us; speedup vs baseline: 1.0567x; 1.0567x over previous
//
#include <hip/hip_runtime.h>
#include <math.h>

#define N_NODES 50000
#define N_EDGES 800000
#define N_GRAPH 2000
#define F_INPUT 34
#define HID 256
#define NLAYER 5

typedef __attribute__((ext_vector_type(8))) short short8;
typedef __attribute__((ext_vector_type(4))) float float4v;

// ---------- helpers ----------
__device__ __forceinline__ float gelu_f(float x) {
  return 0.5f * x * (1.0f + erff(x * 0.70710678118654752440f));
}
__device__ __forceinline__ unsigned short bfr(float f) {  // fp32 -> bf16 RNE
  unsigned u = __float_as_uint(f);
  return (unsigned short)((u + 0x7fffu + ((u >> 16) & 1u)) >> 16);
}
__device__ __forceinline__ float b2f(unsigned short s) {
  return __uint_as_float(((unsigned)s) << 16);
}
__device__ __forceinline__ float4 ld4bf(const unsigned short* p) {
  ushort4 u = *(const ushort4*)p;
  float4 f;
  f.x = b2f(u.x); f.y = b2f(u.y); f.z = b2f(u.z); f.w = b2f(u.w);
  return f;
}
// async global->LDS, 16B per lane; lds dest = wave-uniform base + lane*16
__device__ __forceinline__ void acp16(const unsigned short* g, unsigned short* l) {
  __builtin_amdgcn_global_load_lds(
      (const __attribute__((address_space(1))) void*)g,
      (__attribute__((address_space(3))) void*)l, 16, 0, 0);
}

// ---------- fp32 GEMM (input embed K=34 only) ----------
__global__ __launch_bounds__(256) void gemm_bias(
    const float* __restrict__ A, const float* __restrict__ B,
    const float* __restrict__ bias, float* __restrict__ C,
    int M, int Nn, int K) {
  __shared__ float As[16][64];
  __shared__ float Bs[16][64];
  int tid = threadIdx.x;
  int tx = tid & 15, ty = tid >> 4;
  int row0 = blockIdx.y * 64;
  int col0 = blockIdx.x * 64;
  float acc[4][4] = {};
  int a_r = tid >> 2;
  int a_c = (tid & 3) * 4;
  int b_r = tid >> 4;
  int b_c = (tid & 15) * 4;

  for (int k0 = 0; k0 < K; k0 += 16) {
    int ar = row0 + a_r;
#pragma unroll
    for (int i = 0; i < 4; ++i) {
      int kc = k0 + a_c + i;
      As[a_c + i][a_r] = (ar < M && kc < K) ? A[(long)ar * K + kc] : 0.f;
    }
    int bk = k0 + b_r;
    if (bk < K) {
      float4 bv = *(const float4*)&B[(long)bk * Nn + col0 + b_c];
      Bs[b_r][b_c + 0] = bv.x; Bs[b_r][b_c + 1] = bv.y;
      Bs[b_r][b_c + 2] = bv.z; Bs[b_r][b_c + 3] = bv.w;
    } else {
      Bs[b_r][b_c + 0] = 0.f; Bs[b_r][b_c + 1] = 0.f;
      Bs[b_r][b_c + 2] = 0.f; Bs[b_r][b_c + 3] = 0.f;
    }
    __syncthreads();
#pragma unroll
    for (int kk = 0; kk < 16; ++kk) {
      float4 a = *(const float4*)&As[kk][ty * 4];
      float4 b = *(const float4*)&Bs[kk][tx * 4];
      float av[4] = {a.x, a.y, a.z, a.w};
      float bv[4] = {b.x, b.y, b.z, b.w};
#pragma unroll
      for (int i = 0; i < 4; ++i)
#pragma unroll
        for (int j = 0; j < 4; ++j) acc[i][j] += av[i] * bv[j];
    }
    __syncthreads();
  }
  float4 bi = *(const float4*)&bias[col0 + tx * 4];
  float bia[4] = {bi.x, bi.y, bi.z, bi.w};
#pragma unroll
  for (int i = 0; i < 4; ++i) {
    int r = row0 + ty * 4 + i;
    if (r < M) {
      float4 o;
      o.x = acc[i][0] + bia[0]; o.y = acc[i][1] + bia[1];
      o.z = acc[i][2] + bia[2]; o.w = acc[i][3] + bia[3];
      *(float4*)&C[(long)r * Nn + col0 + tx * 4] = o;
    }
  }
}

// ---------- bf16 MFMA GEMM (m97-style async LDS staging) ----------
__global__ __launch_bounds__(256) void gemm_mfma(
    const unsigned short* __restrict__ A, const unsigned short* __restrict__ Bt,
    const float* __restrict__ bias, void* __restrict__ Cv,
    int M, int Nn, int K, int flags) {
  __shared__ unsigned short smem[12288];  // As[128][32]@0, Bs@4096; epilogue overlay
  unsigned short* As = smem;
  unsigned short* Bs = smem + 4096;
  int tid = threadIdx.x;
  int wave = tid >> 6, lane = tid & 63;
  int row0 = blockIdx.y * 128;
  int col0 = blockIdx.x * 128;
  int wm0 = (wave >> 1) * 64;
  int wn0 = (wave & 1) * 64;
  int q = lane >> 4;
  int ln = lane & 15;

  int srow = wave * 16 + (lane >> 2);
  int scol = (lane & 3) * 8;
  int ra0 = min(row0 + srow, M - 1);
  int ra1 = min(row0 + srow + 64, M - 1);
  const unsigned short* pa0 = A + (size_t)ra0 * K + scol;
  const unsigned short* pa1 = A + (size_t)ra1 * K + scol;
  const unsigned short* pb0 = Bt + (size_t)(col0 + srow) * K + scol;
  const unsigned short* pb1 = Bt + (size_t)(col0 + srow + 64) * K + scol;
  unsigned short* la0 = As + wave * 512;
  unsigned short* la1 = As + wave * 512 + 2048;
  unsigned short* lb0 = Bs + wave * 512;
  unsigned short* lb1 = Bs + wave * 512 + 2048;

  float4v acc[4][4];
#pragma unroll
  for (int i = 0; i < 4; ++i)
#pragma unroll
    for (int j = 0; j < 4; ++j) acc[i][j] = (float4v)0.f;

  for (int k0 = 0; k0 < K; k0 += 32) {
    acp16(pa0 + k0, la0);
    acp16(pa1 + k0, la1);
    acp16(pb0 + k0, lb0);
    acp16(pb1 + k0, lb1);
    __syncthreads();
    short8 af[4], bf[4];
#pragma unroll
    for (int i = 0; i < 4; ++i)
      af[i] = *(const short8*)&As[(wm0 + i * 16 + ln) * 32 + q * 8];
#pragma unroll
    for (int j = 0; j < 4; ++j)
      bf[j] = *(const short8*)&Bs[(wn0 + j * 16 + ln) * 32 + q * 8];
#pragma unroll
    for (int i = 0; i < 4; ++i)
#pragma unroll
      for (int j = 0; j < 4; ++j)
        acc[i][j] = __builtin_amdgcn_mfma_f32_16x16x32_bf16(af[i], bf[j], acc[i][j], 0, 0, 0);
    __syncthreads();
  }
  int rb = (lane >> 4) * 4;
  if (flags & 2) {
    unsigned short* Cb = (unsigned short*)Cv;
    unsigned short* eb = smem + wave * 2560;  // 64 rows x stride 40
#pragma unroll
    for (int p = 0; p < 2; ++p) {
#pragma unroll
      for (int jj = 0; jj < 2; ++jj) {
        int j = p * 2 + jj;
        float bv = bias[col0 + wn0 + j * 16 + ln];
#pragma unroll
        for (int i = 0; i < 4; ++i)
#pragma unroll
          for (int r = 0; r < 4; ++r)
            eb[(i * 16 + rb + r) * 40 + jj * 16 + ln] = bfr(acc[i][j][r] + bv);
      }
      int grow = row0 + wm0 + lane;
      uint4 w0 = *(uint4*)&eb[lane * 40 + 0];
      uint4 w1 = *(uint4*)&eb[lane * 40 + 8];
      uint4 w2 = *(uint4*)&eb[lane * 40 + 16];
      uint4 w3 = *(uint4*)&eb[lane * 40 + 24];
      if (grow < M) {
        unsigned short* dst = Cb + (size_t)grow * Nn + col0 + wn0 + p * 32;
        *(uint4*)&dst[0] = w0;
        *(uint4*)&dst[8] = w1;
        *(uint4*)&dst[16] = w2;
        *(uint4*)&dst[24] = w3;
      }
    }
  } else {
    float* C = (float*)Cv;
#pragma unroll
    for (int j = 0; j < 4; ++j) {
      int col = col0 + wn0 + j * 16 + ln;
      float bv = bias[col];
#pragma unroll
      for (int i = 0; i < 4; ++i)
#pragma unroll
        for (int r = 0; r < 4; ++r) {
          int row = row0 + wm0 + i * 16 + rb + r;
          if (row < M) C[(size_t)row * Nn + col] = acc[i][j][r] + bv;
        }
    }
  }
}

// ---------- weight prep ----------
__global__ __launch_bounds__(256) void prep_w(
    const float* __restrict__ Wl, const float* __restrict__ Wr,
    const float* __restrict__ Wq, const float* __restrict__ Wk,
    const float* __restrict__ Wv, const float* __restrict__ Wsk,
    unsigned short* __restrict__ out) {
  __shared__ float t[32][33];
  int m = blockIdx.z;
  const float* W = (m < 10) ? (((m & 1) ? Wr : Wl) + (size_t)(m >> 1) * 65536)
                 : (m == 10) ? Wq : (m == 11) ? Wk : (m == 12) ? Wv : Wsk;
  int k0 = blockIdx.y * 32, n0 = blockIdx.x * 32;
  int r = threadIdx.x >> 5, c = threadIdx.x & 31;
  for (int rr = r; rr < 32; rr += 8)
    t[rr][c] = W[(size_t)(k0 + rr) * HID + n0 + c];
  __syncthreads();
  unsigned short* o = out + (size_t)m * 65536;
  for (int rr = r; rr < 32; rr += 8)
    o[(size_t)(n0 + rr) * HID + k0 + c] = bfr(t[c][rr]);
}

__global__ __launch_bounds__(256) void prep_wout(const float* __restrict__ W,
                                                 unsigned short* __restrict__ o) {
  __shared__ float t[32][33];
  int k0 = blockIdx.y * 32, n0 = blockIdx.x * 32;
  int r = threadIdx.x >> 5, c = threadIdx.x & 31;
  for (int rr = r; rr < 32; rr += 8)
    t[rr][c] = W[(size_t)(k0 + rr) * 512 + n0 + c];
  __syncthreads();
  for (int rr = r; rr < 32; rr += 8)
    o[(size_t)(n0 + rr) * 512 + k0 + c] = bfr(t[c][rr]);
}

__global__ __launch_bounds__(256) void prep_bias(
    const float* __restrict__ bl, const float* __restrict__ br,
    const float* __restrict__ bq, const float* __restrict__ bk,
    const float* __restrict__ bv, float* __restrict__ out) {
  int i = blockIdx.x * 256 + threadIdx.x;
  if (i < 2560) {
    int l = i >> 9, c = i & 511;
    out[i] = (c < 256) ? bl[l * 256 + c] : br[l * 256 + (c - 256)];
  } else if (i < 3328) {
    int j = i - 2560;
    out[i] = (j < 256) ? bq[j] : (j < 512) ? bk[j - 256] : bv[j - 512];
  }
}

// ---------- LayerNorm standalone (embed + final out) ----------
__global__ __launch_bounds__(256) void ln_act(
    const float* __restrict__ in, const float* __restrict__ gam,
    const float* __restrict__ bet, float* __restrict__ out,
    unsigned short* __restrict__ outb,
    int n_rows, int width, int do_gelu) {
  int wid = blockIdx.x * 4 + (threadIdx.x >> 6);
  int lane = threadIdx.x & 63;
  if (wid >= n_rows) return;
  int chunks = width >> 8;
  float4 v[2];
  float s = 0.f;
  for (int c = 0; c < chunks; ++c) {
    int off = c * 256 + lane * 4;
    float4 t = *(const float4*)&in[(size_t)wid * width + off];
    v[c] = t;
    s += t.x + t.y + t.z + t.w;
  }
  for (int o = 1; o < 64; o <<= 1) s += __shfl_xor(s, o);
  float mean = s / (float)width;
  float vs = 0.f;
  for (int c = 0; c < chunks; ++c) {
    float dx = v[c].x - mean, dy = v[c].y - mean, dz = v[c].z - mean, dw = v[c].w - mean;
    vs += dx * dx + dy * dy + dz * dz + dw * dw;
  }
  for (int o = 1; o < 64; o <<= 1) vs += __shfl_xor(vs, o);
  float inv = rsqrtf(vs / (float)width + 1e-5f);
  for (int c = 0; c < chunks; ++c) {
    int off = c * 256 + lane * 4;
    float4 g4 = *(const float4*)&gam[off];
    float4 b4 = *(const float4*)&bet[off];
    float y[4] = {(v[c].x - mean) * inv * g4.x + b4.x,
                  (v[c].y - mean) * inv * g4.y + b4.y,
                  (v[c].z - mean) * inv * g4.z + b4.z,
                  (v[c].w - mean) * inv * g4.w + b4.w};
    if (do_gelu) {
#pragma unroll
      for (int i = 0; i < 4; ++i) y[i] = gelu_f(y[i]);
    }
    size_t idx = (size_t)wid * width + off;
    float4 o4 = {y[0], y[1], y[2], y[3]};
    *(float4*)&out[idx] = o4;
    if (outb) {
      ushort4 ob = {bfr(y[0]), bfr(y[1]), bfr(y[2]), bfr(y[3])};
      *(ushort4*)&outb[idx] = ob;
    }
  }
}

// ---------- CSR build (two-level scan) ----------
__global__ __launch_bounds__(256) void edge_count(const int* __restrict__ ei,
                                                  int* __restrict__ counts) {
  int e = blockIdx.x * 256 + threadIdx.x;
  if (e < N_EDGES) atomicAdd(&counts[ei[N_EDGES + e]], 1);
}

__global__ __launch_bounds__(1024) void scan1(const int* __restrict__ counts,
                                              int* __restrict__ indptr,
                                              int* __restrict__ bsums, int n) {
  __shared__ int sm[1024];
  int tid = threadIdx.x;
  int i = blockIdx.x * 1024 + tid;
  int v = (i < n) ? counts[i] : 0;
  sm[tid] = v;
  __syncthreads();
  for (int off = 1; off < 1024; off <<= 1) {
    int t = (tid >= off) ? sm[tid - off] : 0;
    __syncthreads();
    sm[tid] += t;
    __syncthreads();
  }
  if (i < n) indptr[i] = sm[tid] - v;
  if (tid == 1023) bsums[blockIdx.x] = sm[1023];
}

__global__ void scan2(int* __restrict__ bsums, int nb) {
  if (threadIdx.x == 0 && blockIdx.x == 0) {
    int acc = 0;
    for (int i = 0; i < nb; ++i) { int t = bsums[i]; bsums[i] = acc; acc += t; }
  }
}

__global__ __launch_bounds__(256) void scan3(const int* __restrict__ bsums,
                                             int* __restrict__ indptr,
                                             int* __restrict__ cursor, int n) {
  int i = blockIdx.x * 256 + threadIdx.x;
  if (i < n) {
    int v = indptr[i] + bsums[i >> 10];
    indptr[i] = v;
    cursor[i] = v;
  }
  if (i == 0) indptr[n] = N_EDGES;
}

__global__ __launch_bounds__(256) void edge_scatter(const int* __restrict__ ei,
                                                    int* __restrict__ cursor,
                                                    int* __restrict__ esrc) {
  int e = blockIdx.x * 256 + threadIdx.x;
  if (e < N_EDGES) {
    int d = ei[N_EDGES + e];
    int p = atomicAdd(&cursor[d], 1);
    esrc[p] = ei[e];
  }
}

// ---------- GATv2 agg + bias + LN + GELU + residual ----------
// 2 waves per node: each wave processes every-other edge (same self-anchor),
// partials combine in LDS, wave 0 of the pair runs the epilogue.
#define GAT_EDGE(f)                                                        \
  {                                                                        \
    float ex = f.x + xri.x; ex = ex > 0.f ? ex : 0.2f * ex;                \
    float ey = f.y + xri.y; ey = ey > 0.f ? ey : 0.2f * ey;                \
    float ez = f.z + xri.z; ez = ez > 0.f ? ez : 0.2f * ez;                \
    float ew = f.w + xri.w; ew = ew > 0.f ? ew : 0.2f * ew;                \
    float p = ex * a4.x + ey * a4.y + ez * a4.z + ew * a4.w;               \
    p += __shfl_xor(p, 1); p += __shfl_xor(p, 2); p += __shfl_xor(p, 4);   \
    float wgt = __expf(fminf(p - m0, 60.f));                               \
    ax += wgt * f.x; ay += wgt * f.y; az += wgt * f.z; aw += wgt * f.w;    \
    lsum += wgt;                                                           \
  }

__global__ __launch_bounds__(256) void gat_agg(
    const unsigned short* __restrict__ xlr, const float* __restrict__ att,
    const int* __restrict__ indptr, const int* __restrict__ esrc,
    const float* __restrict__ pre_bias, const float* __restrict__ gam,
    const float* __restrict__ bet, float* __restrict__ h,
    unsigned short* __restrict__ hb) {
  __shared__ float comb[2][5][64];
  int tid = threadIdx.x;
  int wave = tid >> 6, lane = tid & 63;
  int pair = wave >> 1, half = wave & 1;
  int wid = blockIdx.x * 2 + pair;  // N_NODES even, grid = N/2: no partial blocks
  float4 xri = ld4bf(&xlr[(size_t)wid * 512 + 256 + lane * 4]);
  float4 a4 = *(const float4*)&att[lane * 4];
  int beg = indptr[wid], end = indptr[wid + 1];

  float m0, lsum, ax, ay, az, aw;
  {  // both waves compute the self-loop anchor; only half 0 keeps its term
    float4 f = ld4bf(&xlr[(size_t)wid * 512 + lane * 4]);
    float ex = f.x + xri.x; ex = ex > 0.f ? ex : 0.2f * ex;
    float ey = f.y + xri.y; ey = ey > 0.f ? ey : 0.2f * ey;
    float ez = f.z + xri.z; ez = ez > 0.f ? ez : 0.2f * ez;
    float ew = f.w + xri.w; ew = ew > 0.f ? ew : 0.2f * ew;
    float p = ex * a4.x + ey * a4.y + ez * a4.z + ew * a4.w;
    p += __shfl_xor(p, 1); p += __shfl_xor(p, 2); p += __shfl_xor(p, 4);
    m0 = p;
    if (half == 0) {
      lsum = 1.f; ax = f.x; ay = f.y; az = f.z; aw = f.w;
    } else {
      lsum = 0.f; ax = 0.f; ay = 0.f; az = 0.f; aw = 0.f;
    }
  }
  int e = beg + half;
  for (; e + 6 < end; e += 8) {  // 4 gathers in flight per wave (8 per node)
    int j0 = esrc[e], j1 = esrc[e + 2], j2 = esrc[e + 4], j3 = esrc[e + 6];
    float4 f0 = ld4bf(&xlr[(size_t)j0 * 512 + lane * 4]);
    float4 f1 = ld4bf(&xlr[(size_t)j1 * 512 + lane * 4]);
    float4 f2 = ld4bf(&xlr[(size_t)j2 * 512 + lane * 4]);
    float4 f3 = ld4bf(&xlr[(size_t)j3 * 512 + lane * 4]);
    GAT_EDGE(f0); GAT_EDGE(f1); GAT_EDGE(f2); GAT_EDGE(f3);
  }
  for (; e < end; e += 2) {
    int j = esrc[e];
    float4 f = ld4bf(&xlr[(size_t)j * 512 + lane * 4]);
    GAT_EDGE(f);
  }
  if (half) {
    comb[pair][0][lane] = ax; comb[pair][1][lane] = ay;
    comb[pair][2][lane] = az; comb[pair][3][lane] = aw;
    comb[pair][4][lane] = lsum;
  }
  __syncthreads();
  if (half) return;
  ax += comb[pair][0][lane]; ay += comb[pair][1][lane];
  az += comb[pair][2][lane]; aw += comb[pair][3][lane];
  lsum += comb[pair][4][lane];

  float inv = 1.f / (lsum + 1e-16f);
  float4 pb = *(const float4*)&pre_bias[lane * 4];
  float y0 = ax * inv + pb.x, y1 = ay * inv + pb.y;
  float y2 = az * inv + pb.z, y3 = aw * inv + pb.w;
  float s = y0 + y1 + y2 + y3;
  for (int o = 1; o < 64; o <<= 1) s += __shfl_xor(s, o);
  float mean = s * (1.f / 256.f);
  float d0 = y0 - mean, d1 = y1 - mean, d2 = y2 - mean, d3 = y3 - mean;
  float vs = d0 * d0 + d1 * d1 + d2 * d2 + d3 * d3;
  for (int o = 1; o < 64; o <<= 1) vs += __shfl_xor(vs, o);
  float inv2 = rsqrtf(vs * (1.f / 256.f) + 1e-5f);
  float4 g4 = *(const float4*)&gam[lane * 4];
  float4 b4 = *(const float4*)&bet[lane * 4];
  size_t idx = (size_t)wid * HID + lane * 4;
  float4 r4 = *(const float4*)&h[idx];
  y0 = gelu_f(d0 * inv2 * g4.x + b4.x) + r4.x;
  y1 = gelu_f(d1 * inv2 * g4.y + b4.y) + r4.y;
  y2 = gelu_f(d2 * inv2 * g4.z + b4.z) + r4.z;
  y3 = gelu_f(d3 * inv2 * g4.w + b4.w) + r4.w;
  float4 o4 = {y0, y1, y2, y3};
  *(float4*)&h[idx] = o4;
  ushort4 ob = {bfr(y0), bfr(y1), bfr(y2), bfr(y3)};
  *(ushort4*)&hb[idx] = ob;
}

// ---------- TransformerConv agg + skip + LN + residual ----------
// 2 waves per node, anchor 0 (branchless, clamp +60), LDS combine.
#define TR_EDGE(kj, vj)                                                    \
  {                                                                        \
    float p = qi.x * kj.x + qi.y * kj.y + qi.z * kj.z + qi.w * kj.w;       \
    p += __shfl_xor(p, 1); p += __shfl_xor(p, 2); p += __shfl_xor(p, 4);   \
    float wgt = __expf(fminf(p * scale, 60.f));                            \
    ax += wgt * vj.x; ay += wgt * vj.y; az += wgt * vj.z; aw += wgt * vj.w;\
    lsum += wgt;                                                           \
  }

__global__ __launch_bounds__(256) void tr_agg(
    const unsigned short* __restrict__ qkv, const int* __restrict__ indptr,
    const int* __restrict__ esrc, const unsigned short* __restrict__ skipb,
    const float* __restrict__ gam, const float* __restrict__ bet,
    float* __restrict__ h) {
  __shared__ float comb[2][5][64];
  int tid = threadIdx.x;
  int wave = tid >> 6, lane = tid & 63;
  int pair = wave >> 1, half = wave & 1;
  int wid = blockIdx.x * 2 + pair;
  float4 qi = ld4bf(&qkv[(size_t)wid * 768 + lane * 4]);
  int beg = indptr[wid], end = indptr[wid + 1];
  float lsum = 0.f;
  float ax = 0.f, ay = 0.f, az = 0.f, aw = 0.f;
  const float scale = 0.17677669529663687f;
  int e = beg + half;
  for (; e + 2 < end; e += 4) {  // 4 gathers in flight per wave (8 per node)
    int j0 = esrc[e], j1 = esrc[e + 2];
    float4 k0 = ld4bf(&qkv[(size_t)j0 * 768 + 256 + lane * 4]);
    float4 v0 = ld4bf(&qkv[(size_t)j0 * 768 + 512 + lane * 4]);
    float4 k1 = ld4bf(&qkv[(size_t)j1 * 768 + 256 + lane * 4]);
    float4 v1 = ld4bf(&qkv[(size_t)j1 * 768 + 512 + lane * 4]);
    TR_EDGE(k0, v0); TR_EDGE(k1, v1);
  }
  for (; e < end; e += 2) {
    int j = esrc[e];
    float4 kj = ld4bf(&qkv[(size_t)j * 768 + 256 + lane * 4]);
    float4 vj = ld4bf(&qkv[(size_t)j * 768 + 512 + lane * 4]);
    TR_EDGE(kj, vj);
  }
  if (half) {
    comb[pair][0][lane] = ax; comb[pair][1][lane] = ay;
    comb[pair][2][lane] = az; comb[pair][3][lane] = aw;
    comb[pair][4][lane] = lsum;
  }
  __syncthreads();
  if (half) return;
  ax += comb[pair][0][lane]; ay += comb[pair][1][lane];
  az += comb[pair][2][lane]; aw += comb[pair][3][lane];
  lsum += comb[pair][4][lane];

  float inv = 1.f / (lsum + 1e-16f);
  size_t idx = (size_t)wid * HID + lane * 4;
  float4 sk = ld4bf(&skipb[idx]);
  float y0 = ax * inv + sk.x, y1 = ay * inv + sk.y;
  float y2 = az * inv + sk.z, y3 = aw * inv + sk.w;
  float s = y0 + y1 + y2 + y3;
  for (int o = 1; o < 64; o <<= 1) s += __shfl_xor(s, o);
  float mean = s * (1.f / 256.f);
  float d0 = y0 - mean, d1 = y1 - mean, d2 = y2 - mean, d3 = y3 - mean;
  float vs = d0 * d0 + d1 * d1 + d2 * d2 + d3 * d3;
  for (int o = 1; o < 64; o <<= 1) vs += __shfl_xor(vs, o);
  float inv2 = rsqrtf(vs * (1.f / 256.f) + 1e-5f);
  float4 g4 = *(const float4*)&gam[lane * 4];
  float4 b4 = *(const float4*)&bet[lane * 4];
  float4 r4 = *(const float4*)&h[idx];
  float4 o4;
  o4.x = r4.x + d0 * inv2 * g4.x + b4.x;
  o4.y = r4.y + d1 * inv2 * g4.y + b4.y;
  o4.z = r4.z + d2 * inv2 * g4.z + b4.z;
  o4.w = r4.w + d3 * inv2 * g4.w + b4.w;
  *(float4*)&h[idx] = o4;
}

// ---------- pooling over sorted batch ----------
__global__ __launch_bounds__(256) void graph_bounds(const int* __restrict__ batch,
                                                    int* __restrict__ gptr) {
  int i = blockIdx.x * 256 + threadIdx.x;
  if (i >= N_NODES) return;
  int b0 = batch[i];
  if (i == 0)
    for (int g = 0; g <= b0; ++g) gptr[g] = 0;
  int b1 = (i + 1 < N_NODES) ? batch[i + 1] : N_GRAPH;
  for (int g = b0 + 1; g <= b1; ++g) gptr[g] = i + 1;
}

__global__ __launch_bounds__(256) void pool_seg(
    const float* __restrict__ h, const int* __restrict__ gptr,
    unsigned short* __restrict__ geb) {
  int g = blockIdx.x, c = threadIdx.x;
  int s = gptr[g], e = gptr[g + 1];
  float sum = 0.f, mx = -INFINITY;
  for (int r = s; r < e; ++r) {
    float vv = h[(size_t)r * HID + c];
    sum += vv;
    mx = fmaxf(mx, vv);
  }
  int cnt = e - s;
  geb[(size_t)g * 512 + c] = bfr(sum / (float)max(cnt, 1));
  geb[(size_t)g * 512 + 256 + c] = bfr(cnt ? mx : 0.f);
}

// ---------- host ----------
static inline void mfma_launch(const unsigned short* A, const unsigned short* Bt,
                               const float* bias, void* C, int M, int Nn, int K,
                               int flags, hipStream_t s) {
  dim3 grid(Nn / 128, (M + 127) / 128);
  gemm_mfma<<<grid, 256, 0, s>>>(A, Bt, bias, C, M, Nn, K, flags);
}

extern "C" void kernel_launch(void* const* d_in, const int* in_sizes, int n_in,
                              void* d_out, int out_size, void* d_ws, size_t ws_size,
                              hipStream_t stream) {
  const float* x       = (const float*)d_in[0];
  const int*   ei      = (const int*)d_in[1];
  const int*   batch   = (const int*)d_in[2];
  const float* in_W    = (const float*)d_in[3];
  const float* in_b    = (const float*)d_in[4];
  const float* in_ln_g = (const float*)d_in[5];
  const float* in_ln_b = (const float*)d_in[6];
  const float* gat_Wl  = (const float*)d_in[7];
  const float* gat_bl  = (const float*)d_in[8];
  const float* gat_Wr  = (const float*)d_in[9];
  const float* gat_br  = (const float*)d_in[10];
  const float* gat_att = (const float*)d_in[11];
  const float* gat_bias= (const float*)d_in[12];
  const float* gat_ln_g= (const float*)d_in[13];
  const float* gat_ln_b= (const float*)d_in[14];
  const float* tr_Wq   = (const float*)d_in[15];
  const float* tr_bq   = (const float*)d_in[16];
  const float* tr_Wk   = (const float*)d_in[17];
  const float* tr_bk   = (const float*)d_in[18];
  const float* tr_Wv   = (const float*)d_in[19];
  const float* tr_bv   = (const float*)d_in[20];
  const float* tr_Wsk  = (const float*)d_in[21];
  const float* tr_bsk  = (const float*)d_in[22];
  const float* tr_ln_g = (const float*)d_in[23];
  const float* tr_ln_b = (const float*)d_in[24];
  const float* out_W   = (const float*)d_in[25];
  const float* out_b   = (const float*)d_in[26];
  const float* out_ln_g= (const float*)d_in[27];
  const float* out_ln_b= (const float*)d_in[28];

  // ---- workspace (256B-aligned) ----
  char* w = (char*)d_ws;
  auto take = [&](size_t bytes) -> char* {
    char* p = w;
    w += (bytes + 255) & ~(size_t)255;
    return p;
  };
  const size_t NB = (size_t)N_NODES * HID * sizeof(float);
  float* h    = (float*)take(NB);
  float* aggO = (float*)take(NB);
  unsigned short* hb  = (unsigned short*)take((size_t)N_NODES * HID * 2);
  unsigned short* xq  = (unsigned short*)take((size_t)N_NODES * 768 * 2);
  unsigned short* wbuf= (unsigned short*)take((size_t)(14 * 65536 + 262144) * 2);
  float* bcat = (float*)take(3328 * sizeof(float));
  int* indptr = (int*)take((N_NODES + 1) * sizeof(int));
  int* cursor = (int*)take(N_NODES * sizeof(int));
  int* counts = (int*)take(N_NODES * sizeof(int));
  int* esrc   = (int*)take(N_EDGES * sizeof(int));
  int* bsums  = (int*)take(64 * sizeof(int));
  unsigned short* skipb = (unsigned short*)aggO;
  char* w2 = (char*)xq;
  auto take2 = [&](size_t bytes) -> char* {
    char* p = w2;
    w2 += (bytes + 255) & ~(size_t)255;
    return p;
  };
  int* gptr = (int*)take2((N_GRAPH + 1) * sizeof(int));
  unsigned short* geb = (unsigned short*)take2((size_t)N_GRAPH * 512 * 2);
  float* tbuf = (float*)take2((size_t)N_GRAPH * 512 * sizeof(float));

  const int EB = (N_EDGES + 255) / 256;
  const int WB = (N_NODES + 3) / 4;
  const int WB2 = N_NODES / 2;  // 2 nodes per block (N even)
  const int NSB = (N_NODES + 1023) / 1024;

  // --- weight/bias prep ---
  {
    dim3 g(8, 8, 14);
    prep_w<<<g, 256, 0, stream>>>(gat_Wl, gat_Wr, tr_Wq, tr_Wk, tr_Wv, tr_Wsk, wbuf);
    dim3 g2(16, 16);
    prep_wout<<<g2, 256, 0, stream>>>(out_W, wbuf + (size_t)14 * 65536);
    prep_bias<<<13, 256, 0, stream>>>(gat_bl, gat_br, tr_bq, tr_bk, tr_bv, bcat);
  }

  // --- CSR (dst-sorted), two-level scan ---
  hipMemsetAsync(counts, 0, N_NODES * sizeof(int), stream);
  edge_count<<<EB, 256, 0, stream>>>(ei, counts);
  scan1<<<NSB, 1024, 0, stream>>>(counts, indptr, bsums, N_NODES);
  scan2<<<1, 64, 0, stream>>>(bsums, NSB);
  scan3<<<(N_NODES + 255) / 256, 256, 0, stream>>>(bsums, indptr, cursor, N_NODES);
  edge_scatter<<<EB, 256, 0, stream>>>(ei, cursor, esrc);

  // --- input embed ---
  {
    dim3 grid(HID / 64, (N_NODES + 63) / 64);
    gemm_bias<<<grid, 256, 0, stream>>>(x, in_W, in_b, aggO, N_NODES, HID, F_INPUT);
  }
  ln_act<<<WB, 256, 0, stream>>>(aggO, in_ln_g, in_ln_b, h, hb, N_NODES, HID, 1);

  // --- 5 GATv2 layers ---
  for (int l = 0; l < NLAYER; ++l) {
    mfma_launch(hb, wbuf + (size_t)(2 * l) * 65536, bcat + l * 512, xq,
                N_NODES, 512, HID, 2, stream);
    gat_agg<<<WB2, 256, 0, stream>>>(xq, gat_att + l * HID, indptr, esrc,
                                     gat_bias + l * HID, gat_ln_g + l * HID,
                                     gat_ln_b + l * HID, h, hb);
  }

  // --- TransformerConv ---
  mfma_launch(hb, wbuf + (size_t)13 * 65536, tr_bsk, skipb,
              N_NODES, HID, HID, 2, stream);
  mfma_launch(hb, wbuf + (size_t)10 * 65536, bcat + 2560, xq,
              N_NODES, 768, HID, 2, stream);
  tr_agg<<<WB2, 256, 0, stream>>>(xq, indptr, esrc, skipb, tr_ln_g, tr_ln_b, h);

  // --- pooling -> geb bf16 ---
  graph_bounds<<<(N_NODES + 255) / 256, 256, 0, stream>>>(batch, gptr);
  pool_seg<<<N_GRAPH, 256, 0, stream>>>(h, gptr, geb);

  // --- output proj (MFMA) + final LN/GELU ---
  mfma_launch(geb, wbuf + (size_t)14 * 65536, out_b, tbuf,
              N_GRAPH, 512, 512, 0, stream);
  ln_act<<<(N_GRAPH + 3) / 4, 256, 0, stream>>>(tbuf, out_ln_g, out_ln_b,
                                                (float*)d_out, nullptr,
                                                N_GRAPH, 512, 1);
}

// Round 9
// 1194.929 us; speedup vs baseline: 1.0658x; 1.0086x over previous
//
#include <hip/hip_runtime.h>
#include <math.h>

#define N_NODES 50000
#define N_EDGES 800000
#define N_GRAPH 2000
#define F_INPUT 34
#define HID 256
#define NLAYER 5

typedef __attribute__((ext_vector_type(8))) short short8;
typedef __attribute__((ext_vector_type(4))) float float4v;

// ---------- helpers ----------
__device__ __forceinline__ float gelu_f(float x) {
  return 0.5f * x * (1.0f + erff(x * 0.70710678118654752440f));
}
__device__ __forceinline__ unsigned short bfr(float f) {  // fp32 -> bf16 RNE
  unsigned u = __float_as_uint(f);
  return (unsigned short)((u + 0x7fffu + ((u >> 16) & 1u)) >> 16);
}
__device__ __forceinline__ float b2f(unsigned short s) {
  return __uint_as_float(((unsigned)s) << 16);
}
__device__ __forceinline__ float4 ld4bf(const unsigned short* p) {
  ushort4 u = *(const ushort4*)p;
  float4 f;
  f.x = b2f(u.x); f.y = b2f(u.y); f.z = b2f(u.z); f.w = b2f(u.w);
  return f;
}
__device__ __forceinline__ void unpk(unsigned u, float& a, float& b) {
  a = __uint_as_float(u << 16);
  b = __uint_as_float(u & 0xffff0000u);
}
// async global->LDS, 16B per lane
__device__ __forceinline__ void acp16(const unsigned short* g, unsigned short* l) {
  __builtin_amdgcn_global_load_lds(
      (const __attribute__((address_space(1))) void*)g,
      (__attribute__((address_space(3))) void*)l, 16, 0, 0);
}

// ---------- fp32 GEMM (input embed K=34 only) ----------
__global__ __launch_bounds__(256) void gemm_bias(
    const float* __restrict__ A, const float* __restrict__ B,
    const float* __restrict__ bias, float* __restrict__ C,
    int M, int Nn, int K) {
  __shared__ float As[16][64];
  __shared__ float Bs[16][64];
  int tid = threadIdx.x;
  int tx = tid & 15, ty = tid >> 4;
  int row0 = blockIdx.y * 64;
  int col0 = blockIdx.x * 64;
  float acc[4][4] = {};
  int a_r = tid >> 2;
  int a_c = (tid & 3) * 4;
  int b_r = tid >> 4;
  int b_c = (tid & 15) * 4;

  for (int k0 = 0; k0 < K; k0 += 16) {
    int ar = row0 + a_r;
#pragma unroll
    for (int i = 0; i < 4; ++i) {
      int kc = k0 + a_c + i;
      As[a_c + i][a_r] = (ar < M && kc < K) ? A[(long)ar * K + kc] : 0.f;
    }
    int bk = k0 + b_r;
    if (bk < K) {
      float4 bv = *(const float4*)&B[(long)bk * Nn + col0 + b_c];
      Bs[b_r][b_c + 0] = bv.x; Bs[b_r][b_c + 1] = bv.y;
      Bs[b_r][b_c + 2] = bv.z; Bs[b_r][b_c + 3] = bv.w;
    } else {
      Bs[b_r][b_c + 0] = 0.f; Bs[b_r][b_c + 1] = 0.f;
      Bs[b_r][b_c + 2] = 0.f; Bs[b_r][b_c + 3] = 0.f;
    }
    __syncthreads();
#pragma unroll
    for (int kk = 0; kk < 16; ++kk) {
      float4 a = *(const float4*)&As[kk][ty * 4];
      float4 b = *(const float4*)&Bs[kk][tx * 4];
      float av[4] = {a.x, a.y, a.z, a.w};
      float bv[4] = {b.x, b.y, b.z, b.w};
#pragma unroll
      for (int i = 0; i < 4; ++i)
#pragma unroll
        for (int j = 0; j < 4; ++j) acc[i][j] += av[i] * bv[j];
    }
    __syncthreads();
  }
  float4 bi = *(const float4*)&bias[col0 + tx * 4];
  float bia[4] = {bi.x, bi.y, bi.z, bi.w};
#pragma unroll
  for (int i = 0; i < 4; ++i) {
    int r = row0 + ty * 4 + i;
    if (r < M) {
      float4 o;
      o.x = acc[i][0] + bia[0]; o.y = acc[i][1] + bia[1];
      o.z = acc[i][2] + bia[2]; o.w = acc[i][3] + bia[3];
      *(float4*)&C[(long)r * Nn + col0 + tx * 4] = o;
    }
  }
}

// ---------- bf16 MFMA GEMM (m97-style async LDS staging) ----------
__global__ __launch_bounds__(256) void gemm_mfma(
    const unsigned short* __restrict__ A, const unsigned short* __restrict__ Bt,
    const float* __restrict__ bias, void* __restrict__ Cv,
    int M, int Nn, int K, int flags) {
  __shared__ unsigned short smem[12288];
  unsigned short* As = smem;
  unsigned short* Bs = smem + 4096;
  int tid = threadIdx.x;
  int wave = tid >> 6, lane = tid & 63;
  int row0 = blockIdx.y * 128;
  int col0 = blockIdx.x * 128;
  int wm0 = (wave >> 1) * 64;
  int wn0 = (wave & 1) * 64;
  int q = lane >> 4;
  int ln = lane & 15;

  int srow = wave * 16 + (lane >> 2);
  int scol = (lane & 3) * 8;
  int ra0 = min(row0 + srow, M - 1);
  int ra1 = min(row0 + srow + 64, M - 1);
  const unsigned short* pa0 = A + (size_t)ra0 * K + scol;
  const unsigned short* pa1 = A + (size_t)ra1 * K + scol;
  const unsigned short* pb0 = Bt + (size_t)(col0 + srow) * K + scol;
  const unsigned short* pb1 = Bt + (size_t)(col0 + srow + 64) * K + scol;
  unsigned short* la0 = As + wave * 512;
  unsigned short* la1 = As + wave * 512 + 2048;
  unsigned short* lb0 = Bs + wave * 512;
  unsigned short* lb1 = Bs + wave * 512 + 2048;

  float4v acc[4][4];
#pragma unroll
  for (int i = 0; i < 4; ++i)
#pragma unroll
    for (int j = 0; j < 4; ++j) acc[i][j] = (float4v)0.f;

  for (int k0 = 0; k0 < K; k0 += 32) {
    acp16(pa0 + k0, la0);
    acp16(pa1 + k0, la1);
    acp16(pb0 + k0, lb0);
    acp16(pb1 + k0, lb1);
    __syncthreads();
    short8 af[4], bf[4];
#pragma unroll
    for (int i = 0; i < 4; ++i)
      af[i] = *(const short8*)&As[(wm0 + i * 16 + ln) * 32 + q * 8];
#pragma unroll
    for (int j = 0; j < 4; ++j)
      bf[j] = *(const short8*)&Bs[(wn0 + j * 16 + ln) * 32 + q * 8];
#pragma unroll
    for (int i = 0; i < 4; ++i)
#pragma unroll
      for (int j = 0; j < 4; ++j)
        acc[i][j] = __builtin_amdgcn_mfma_f32_16x16x32_bf16(af[i], bf[j], acc[i][j], 0, 0, 0);
    __syncthreads();
  }
  int rb = (lane >> 4) * 4;
  if (flags & 2) {
    unsigned short* Cb = (unsigned short*)Cv;
    unsigned short* eb = smem + wave * 2560;
#pragma unroll
    for (int p = 0; p < 2; ++p) {
#pragma unroll
      for (int jj = 0; jj < 2; ++jj) {
        int j = p * 2 + jj;
        float bv = bias[col0 + wn0 + j * 16 + ln];
#pragma unroll
        for (int i = 0; i < 4; ++i)
#pragma unroll
          for (int r = 0; r < 4; ++r)
            eb[(i * 16 + rb + r) * 40 + jj * 16 + ln] = bfr(acc[i][j][r] + bv);
      }
      int grow = row0 + wm0 + lane;
      uint4 w0 = *(uint4*)&eb[lane * 40 + 0];
      uint4 w1 = *(uint4*)&eb[lane * 40 + 8];
      uint4 w2 = *(uint4*)&eb[lane * 40 + 16];
      uint4 w3 = *(uint4*)&eb[lane * 40 + 24];
      if (grow < M) {
        unsigned short* dst = Cb + (size_t)grow * Nn + col0 + wn0 + p * 32;
        *(uint4*)&dst[0] = w0;
        *(uint4*)&dst[8] = w1;
        *(uint4*)&dst[16] = w2;
        *(uint4*)&dst[24] = w3;
      }
    }
  } else {
    float* C = (float*)Cv;
#pragma unroll
    for (int j = 0; j < 4; ++j) {
      int col = col0 + wn0 + j * 16 + ln;
      float bv = bias[col];
#pragma unroll
      for (int i = 0; i < 4; ++i)
#pragma unroll
        for (int r = 0; r < 4; ++r) {
          int row = row0 + wm0 + i * 16 + rb + r;
          if (row < M) C[(size_t)row * Nn + col] = acc[i][j][r] + bv;
        }
    }
  }
}

// ---------- weight prep: Wt_bf16[n][k] = bf16(W[k][n]) ----------
// slots: 2l=Wl_l, 2l+1=Wr_l (l<5); 10=q, 11=k, 12=v, 13=skip.
// k/v columns are interleaved into the fused qkv region: col c of K -> fused
// row 256 + (c>>2)*8 + (c&3); col c of V -> 256 + (c>>2)*8 + 4 + (c&3).
__global__ __launch_bounds__(256) void prep_w(
    const float* __restrict__ Wl, const float* __restrict__ Wr,
    const float* __restrict__ Wq, const float* __restrict__ Wk,
    const float* __restrict__ Wv, const float* __restrict__ Wsk,
    unsigned short* __restrict__ out) {
  __shared__ float t[32][33];
  int m = blockIdx.z;
  const float* W = (m < 10) ? (((m & 1) ? Wr : Wl) + (size_t)(m >> 1) * 65536)
                 : (m == 10) ? Wq : (m == 11) ? Wk : (m == 12) ? Wv : Wsk;
  int k0 = blockIdx.y * 32, n0 = blockIdx.x * 32;
  int r = threadIdx.x >> 5, c = threadIdx.x & 31;
  for (int rr = r; rr < 32; rr += 8)
    t[rr][c] = W[(size_t)(k0 + rr) * HID + n0 + c];
  __syncthreads();
  for (int rr = r; rr < 32; rr += 8) {
    int n = n0 + rr;
    unsigned short* o;
    int drow;
    if (m == 11) {
      o = out + (size_t)10 * 65536;
      drow = 256 + (n >> 2) * 8 + (n & 3);
    } else if (m == 12) {
      o = out + (size_t)10 * 65536;
      drow = 256 + (n >> 2) * 8 + 4 + (n & 3);
    } else {
      o = out + (size_t)m * 65536;
      drow = n;
    }
    o[(size_t)drow * HID + k0 + c] = bfr(t[c][rr]);
  }
}

__global__ __launch_bounds__(256) void prep_wout(const float* __restrict__ W,
                                                 unsigned short* __restrict__ o) {
  __shared__ float t[32][33];
  int k0 = blockIdx.y * 32, n0 = blockIdx.x * 32;
  int r = threadIdx.x >> 5, c = threadIdx.x & 31;
  for (int rr = r; rr < 32; rr += 8)
    t[rr][c] = W[(size_t)(k0 + rr) * 512 + n0 + c];
  __syncthreads();
  for (int rr = r; rr < 32; rr += 8)
    o[(size_t)(n0 + rr) * 512 + k0 + c] = bfr(t[c][rr]);
}

// concat biases: [5][512] = bl|br per layer; then [768] = bq | interleaved bk/bv
__global__ __launch_bounds__(256) void prep_bias(
    const float* __restrict__ bl, const float* __restrict__ br,
    const float* __restrict__ bq, const float* __restrict__ bk,
    const float* __restrict__ bv, float* __restrict__ out) {
  int i = blockIdx.x * 256 + threadIdx.x;
  if (i < 2560) {
    int l = i >> 9, c = i & 511;
    out[i] = (c < 256) ? bl[l * 256 + c] : br[l * 256 + (c - 256)];
  } else if (i < 3328) {
    int j = i - 2560;
    if (j < 256) {
      out[i] = bq[j];
    } else {
      int t = j - 256, g = t >> 3, r = t & 7;
      out[i] = (r < 4) ? bk[4 * g + r] : bv[4 * g + (r - 4)];
    }
  }
}

// ---------- LayerNorm standalone (embed + final out) ----------
__global__ __launch_bounds__(256) void ln_act(
    const float* __restrict__ in, const float* __restrict__ gam,
    const float* __restrict__ bet, float* __restrict__ out,
    unsigned short* __restrict__ outb,
    int n_rows, int width, int do_gelu) {
  int wid = blockIdx.x * 4 + (threadIdx.x >> 6);
  int lane = threadIdx.x & 63;
  if (wid >= n_rows) return;
  int chunks = width >> 8;
  float4 v[2];
  float s = 0.f;
  for (int c = 0; c < chunks; ++c) {
    int off = c * 256 + lane * 4;
    float4 t = *(const float4*)&in[(size_t)wid * width + off];
    v[c] = t;
    s += t.x + t.y + t.z + t.w;
  }
  for (int o = 1; o < 64; o <<= 1) s += __shfl_xor(s, o);
  float mean = s / (float)width;
  float vs = 0.f;
  for (int c = 0; c < chunks; ++c) {
    float dx = v[c].x - mean, dy = v[c].y - mean, dz = v[c].z - mean, dw = v[c].w - mean;
    vs += dx * dx + dy * dy + dz * dz + dw * dw;
  }
  for (int o = 1; o < 64; o <<= 1) vs += __shfl_xor(vs, o);
  float inv = rsqrtf(vs / (float)width + 1e-5f);
  for (int c = 0; c < chunks; ++c) {
    int off = c * 256 + lane * 4;
    float4 g4 = *(const float4*)&gam[off];
    float4 b4 = *(const float4*)&bet[off];
    float y[4] = {(v[c].x - mean) * inv * g4.x + b4.x,
                  (v[c].y - mean) * inv * g4.y + b4.y,
                  (v[c].z - mean) * inv * g4.z + b4.z,
                  (v[c].w - mean) * inv * g4.w + b4.w};
    if (do_gelu) {
#pragma unroll
      for (int i = 0; i < 4; ++i) y[i] = gelu_f(y[i]);
    }
    size_t idx = (size_t)wid * width + off;
    float4 o4 = {y[0], y[1], y[2], y[3]};
    *(float4*)&out[idx] = o4;
    if (outb) {
      ushort4 ob = {bfr(y[0]), bfr(y[1]), bfr(y[2]), bfr(y[3])};
      *(ushort4*)&outb[idx] = ob;
    }
  }
}

// ---------- CSR build ----------
__global__ __launch_bounds__(256) void edge_count(const int* __restrict__ ei,
                                                  int* __restrict__ counts) {
  int e = blockIdx.x * 256 + threadIdx.x;
  if (e < N_EDGES) atomicAdd(&counts[ei[N_EDGES + e]], 1);
}

__global__ __launch_bounds__(1024) void scan1(const int* __restrict__ counts,
                                              int* __restrict__ indptr,
                                              int* __restrict__ bsums, int n) {
  __shared__ int sm[1024];
  int tid = threadIdx.x;
  int i = blockIdx.x * 1024 + tid;
  int v = (i < n) ? counts[i] : 0;
  sm[tid] = v;
  __syncthreads();
  for (int off = 1; off < 1024; off <<= 1) {
    int t = (tid >= off) ? sm[tid - off] : 0;
    __syncthreads();
    sm[tid] += t;
    __syncthreads();
  }
  if (i < n) indptr[i] = sm[tid] - v;
  if (tid == 1023) bsums[blockIdx.x] = sm[1023];
}

// scan3 absorbs the block-sum prefix (uniform short loop; blk = blockIdx>>2)
__global__ __launch_bounds__(256) void scan3(const int* __restrict__ bsums,
                                             int* __restrict__ indptr,
                                             int* __restrict__ cursor, int n) {
  int i = blockIdx.x * 256 + threadIdx.x;
  int blk = blockIdx.x >> 2;  // 256-blocks per 1024-scan-block: uniform
  int off = 0;
  for (int b = 0; b < blk; ++b) off += bsums[b];
  if (i < n) {
    int v = indptr[i] + off;
    indptr[i] = v;
    cursor[i] = v;
  }
  if (i == 0) indptr[n] = N_EDGES;
}

__global__ __launch_bounds__(256) void edge_scatter(const int* __restrict__ ei,
                                                    int* __restrict__ cursor,
                                                    int* __restrict__ esrc) {
  int e = blockIdx.x * 256 + threadIdx.x;
  if (e < N_EDGES) {
    int d = ei[N_EDGES + e];
    int p = atomicAdd(&cursor[d], 1);
    esrc[p] = ei[e];
  }
}

// ---------- GATv2 agg + bias + LN + GELU + residual (R6 winner) ----------
#define GAT_EDGE(f)                                                        \
  {                                                                        \
    float ex = f.x + xri.x; ex = ex > 0.f ? ex : 0.2f * ex;                \
    float ey = f.y + xri.y; ey = ey > 0.f ? ey : 0.2f * ey;                \
    float ez = f.z + xri.z; ez = ez > 0.f ? ez : 0.2f * ez;                \
    float ew = f.w + xri.w; ew = ew > 0.f ? ew : 0.2f * ew;                \
    float p = ex * a4.x + ey * a4.y + ez * a4.z + ew * a4.w;               \
    p += __shfl_xor(p, 1); p += __shfl_xor(p, 2); p += __shfl_xor(p, 4);   \
    float wgt = __expf(fminf(p - m0, 60.f));                               \
    ax += wgt * f.x; ay += wgt * f.y; az += wgt * f.z; aw += wgt * f.w;    \
    lsum += wgt;                                                           \
  }

__global__ __launch_bounds__(256) void gat_agg(
    const unsigned short* __restrict__ xlr, const float* __restrict__ att,
    const int* __restrict__ indptr, const int* __restrict__ esrc,
    const float* __restrict__ pre_bias, const float* __restrict__ gam,
    const float* __restrict__ bet, float* __restrict__ h,
    unsigned short* __restrict__ hb) {
  int wid = blockIdx.x * 4 + (threadIdx.x >> 6);
  int lane = threadIdx.x & 63;
  if (wid >= N_NODES) return;
  float4 xri = ld4bf(&xlr[(size_t)wid * 512 + 256 + lane * 4]);
  float4 a4 = *(const float4*)&att[lane * 4];
  int beg = indptr[wid], end = indptr[wid + 1];

  float m0, lsum, ax, ay, az, aw;
  {  // self loop = softmax anchor
    float4 f = ld4bf(&xlr[(size_t)wid * 512 + lane * 4]);
    float ex = f.x + xri.x; ex = ex > 0.f ? ex : 0.2f * ex;
    float ey = f.y + xri.y; ey = ey > 0.f ? ey : 0.2f * ey;
    float ez = f.z + xri.z; ez = ez > 0.f ? ez : 0.2f * ez;
    float ew = f.w + xri.w; ew = ew > 0.f ? ew : 0.2f * ew;
    float p = ex * a4.x + ey * a4.y + ez * a4.z + ew * a4.w;
    p += __shfl_xor(p, 1); p += __shfl_xor(p, 2); p += __shfl_xor(p, 4);
    m0 = p; lsum = 1.f;
    ax = f.x; ay = f.y; az = f.z; aw = f.w;
  }
  int e = beg;
  for (; e + 7 < end; e += 8) {
    int j0 = esrc[e],     j1 = esrc[e + 1], j2 = esrc[e + 2], j3 = esrc[e + 3];
    int j4 = esrc[e + 4], j5 = esrc[e + 5], j6 = esrc[e + 6], j7 = esrc[e + 7];
    float4 f0 = ld4bf(&xlr[(size_t)j0 * 512 + lane * 4]);
    float4 f1 = ld4bf(&xlr[(size_t)j1 * 512 + lane * 4]);
    float4 f2 = ld4bf(&xlr[(size_t)j2 * 512 + lane * 4]);
    float4 f3 = ld4bf(&xlr[(size_t)j3 * 512 + lane * 4]);
    float4 f4 = ld4bf(&xlr[(size_t)j4 * 512 + lane * 4]);
    float4 f5 = ld4bf(&xlr[(size_t)j5 * 512 + lane * 4]);
    float4 f6 = ld4bf(&xlr[(size_t)j6 * 512 + lane * 4]);
    float4 f7 = ld4bf(&xlr[(size_t)j7 * 512 + lane * 4]);
    GAT_EDGE(f0); GAT_EDGE(f1); GAT_EDGE(f2); GAT_EDGE(f3);
    GAT_EDGE(f4); GAT_EDGE(f5); GAT_EDGE(f6); GAT_EDGE(f7);
  }
  for (; e + 3 < end; e += 4) {
    int j0 = esrc[e], j1 = esrc[e + 1], j2 = esrc[e + 2], j3 = esrc[e + 3];
    float4 f0 = ld4bf(&xlr[(size_t)j0 * 512 + lane * 4]);
    float4 f1 = ld4bf(&xlr[(size_t)j1 * 512 + lane * 4]);
    float4 f2 = ld4bf(&xlr[(size_t)j2 * 512 + lane * 4]);
    float4 f3 = ld4bf(&xlr[(size_t)j3 * 512 + lane * 4]);
    GAT_EDGE(f0); GAT_EDGE(f1); GAT_EDGE(f2); GAT_EDGE(f3);
  }
  for (; e < end; ++e) {
    int j = esrc[e];
    float4 f = ld4bf(&xlr[(size_t)j * 512 + lane * 4]);
    GAT_EDGE(f);
  }
  float inv = 1.f / (lsum + 1e-16f);
  float4 pb = *(const float4*)&pre_bias[lane * 4];
  float y0 = ax * inv + pb.x, y1 = ay * inv + pb.y;
  float y2 = az * inv + pb.z, y3 = aw * inv + pb.w;
  float s = y0 + y1 + y2 + y3;
  for (int o = 1; o < 64; o <<= 1) s += __shfl_xor(s, o);
  float mean = s * (1.f / 256.f);
  float d0 = y0 - mean, d1 = y1 - mean, d2 = y2 - mean, d3 = y3 - mean;
  float vs = d0 * d0 + d1 * d1 + d2 * d2 + d3 * d3;
  for (int o = 1; o < 64; o <<= 1) vs += __shfl_xor(vs, o);
  float inv2 = rsqrtf(vs * (1.f / 256.f) + 1e-5f);
  float4 g4 = *(const float4*)&gam[lane * 4];
  float4 b4 = *(const float4*)&bet[lane * 4];
  size_t idx = (size_t)wid * HID + lane * 4;
  float4 r4 = *(const float4*)&h[idx];
  y0 = gelu_f(d0 * inv2 * g4.x + b4.x) + r4.x;
  y1 = gelu_f(d1 * inv2 * g4.y + b4.y) + r4.y;
  y2 = gelu_f(d2 * inv2 * g4.z + b4.z) + r4.z;
  y3 = gelu_f(d3 * inv2 * g4.w + b4.w) + r4.w;
  float4 o4 = {y0, y1, y2, y3};
  *(float4*)&h[idx] = o4;
  ushort4 ob = {bfr(y0), bfr(y1), bfr(y2), bfr(y3)};
  *(ushort4*)&hb[idx] = ob;
}

// ---------- TransformerConv agg (2 waves/node, interleaved kv loads) ----------
// qkv row layout: [q(256)] then 64 groups of [k0..k3|v0..v3] (16B per lane).
#define TR_EDGE_I(u)                                                       \
  {                                                                        \
    float kx, ky, kz, kw, vx, vy, vz, vw;                                  \
    unpk(u.x, kx, ky); unpk(u.y, kz, kw);                                  \
    unpk(u.z, vx, vy); unpk(u.w, vz, vw);                                  \
    float p = qi.x * kx + qi.y * ky + qi.z * kz + qi.w * kw;               \
    p += __shfl_xor(p, 1); p += __shfl_xor(p, 2); p += __shfl_xor(p, 4);   \
    float wgt = __expf(fminf(p * scale, 60.f));                            \
    ax += wgt * vx; ay += wgt * vy; az += wgt * vz; aw += wgt * vw;        \
    lsum += wgt;                                                           \
  }

__global__ __launch_bounds__(256) void tr_agg(
    const unsigned short* __restrict__ qkv, const int* __restrict__ indptr,
    const int* __restrict__ esrc, const unsigned short* __restrict__ skipb,
    const float* __restrict__ gam, const float* __restrict__ bet,
    float* __restrict__ h) {
  __shared__ float comb[2][5][64];
  int tid = threadIdx.x;
  int wave = tid >> 6, lane = tid & 63;
  int pair = wave >> 1, half = wave & 1;
  int wid = blockIdx.x * 2 + pair;  // N even: no partial blocks
  float4 qi = ld4bf(&qkv[(size_t)wid * 768 + lane * 4]);
  int beg = indptr[wid], end = indptr[wid + 1];
  float lsum = 0.f;
  float ax = 0.f, ay = 0.f, az = 0.f, aw = 0.f;
  const float scale = 0.17677669529663687f;
  int e = beg + half;
  for (; e + 6 < end; e += 8) {  // 4 x 16B gathers in flight per wave
    int j0 = esrc[e], j1 = esrc[e + 2], j2 = esrc[e + 4], j3 = esrc[e + 6];
    uint4 u0 = *(const uint4*)&qkv[(size_t)j0 * 768 + 256 + lane * 8];
    uint4 u1 = *(const uint4*)&qkv[(size_t)j1 * 768 + 256 + lane * 8];
    uint4 u2 = *(const uint4*)&qkv[(size_t)j2 * 768 + 256 + lane * 8];
    uint4 u3 = *(const uint4*)&qkv[(size_t)j3 * 768 + 256 + lane * 8];
    TR_EDGE_I(u0); TR_EDGE_I(u1); TR_EDGE_I(u2); TR_EDGE_I(u3);
  }
  for (; e < end; e += 2) {
    int j = esrc[e];
    uint4 u = *(const uint4*)&qkv[(size_t)j * 768 + 256 + lane * 8];
    TR_EDGE_I(u);
  }
  if (half) {
    comb[pair][0][lane] = ax; comb[pair][1][lane] = ay;
    comb[pair][2][lane] = az; comb[pair][3][lane] = aw;
    comb[pair][4][lane] = lsum;
  }
  __syncthreads();
  if (half) return;
  ax += comb[pair][0][lane]; ay += comb[pair][1][lane];
  az += comb[pair][2][lane]; aw += comb[pair][3][lane];
  lsum += comb[pair][4][lane];

  float inv = 1.f / (lsum + 1e-16f);
  size_t idx = (size_t)wid * HID + lane * 4;
  float4 sk = ld4bf(&skipb[idx]);
  float y0 = ax * inv + sk.x, y1 = ay * inv + sk.y;
  float y2 = az * inv + sk.z, y3 = aw * inv + sk.w;
  float s = y0 + y1 + y2 + y3;
  for (int o = 1; o < 64; o <<= 1) s += __shfl_xor(s, o);
  float mean = s * (1.f / 256.f);
  float d0 = y0 - mean, d1 = y1 - mean, d2 = y2 - mean, d3 = y3 - mean;
  float vs = d0 * d0 + d1 * d1 + d2 * d2 + d3 * d3;
  for (int o = 1; o < 64; o <<= 1) vs += __shfl_xor(vs, o);
  float inv2 = rsqrtf(vs * (1.f / 256.f) + 1e-5f);
  float4 g4 = *(const float4*)&gam[lane * 4];
  float4 b4 = *(const float4*)&bet[lane * 4];
  float4 r4 = *(const float4*)&h[idx];
  float4 o4;
  o4.x = r4.x + d0 * inv2 * g4.x + b4.x;
  o4.y = r4.y + d1 * inv2 * g4.y + b4.y;
  o4.z = r4.z + d2 * inv2 * g4.z + b4.z;
  o4.w = r4.w + d3 * inv2 * g4.w + b4.w;
  *(float4*)&h[idx] = o4;
}

// ---------- pooling over sorted batch (inline binary search) ----------
__global__ __launch_bounds__(256) void pool_seg(
    const float* __restrict__ h, const int* __restrict__ batch,
    unsigned short* __restrict__ geb) {
  int g = blockIdx.x, c = threadIdx.x;
  int lo = 0, hi = N_NODES;
  while (lo < hi) { int mid = (lo + hi) >> 1; if (batch[mid] < g) lo = mid + 1; else hi = mid; }
  int s = lo;
  hi = N_NODES;
  while (lo < hi) { int mid = (lo + hi) >> 1; if (batch[mid] < g + 1) lo = mid + 1; else hi = mid; }
  int e = lo;
  float sum = 0.f, mx = -INFINITY;
  for (int r = s; r < e; ++r) {
    float vv = h[(size_t)r * HID + c];
    sum += vv;
    mx = fmaxf(mx, vv);
  }
  int cnt = e - s;
  geb[(size_t)g * 512 + c] = bfr(sum / (float)max(cnt, 1));
  geb[(size_t)g * 512 + 256 + c] = bfr(cnt ? mx : 0.f);
}

// ---------- host ----------
static inline void mfma_launch(const unsigned short* A, const unsigned short* Bt,
                               const float* bias, void* C, int M, int Nn, int K,
                               int flags, hipStream_t s) {
  dim3 grid(Nn / 128, (M + 127) / 128);
  gemm_mfma<<<grid, 256, 0, s>>>(A, Bt, bias, C, M, Nn, K, flags);
}

extern "C" void kernel_launch(void* const* d_in, const int* in_sizes, int n_in,
                              void* d_out, int out_size, void* d_ws, size_t ws_size,
                              hipStream_t stream) {
  const float* x       = (const float*)d_in[0];
  const int*   ei      = (const int*)d_in[1];
  const int*   batch   = (const int*)d_in[2];
  const float* in_W    = (const float*)d_in[3];
  const float* in_b    = (const float*)d_in[4];
  const float* in_ln_g = (const float*)d_in[5];
  const float* in_ln_b = (const float*)d_in[6];
  const float* gat_Wl  = (const float*)d_in[7];
  const float* gat_bl  = (const float*)d_in[8];
  const float* gat_Wr  = (const float*)d_in[9];
  const float* gat_br  = (const float*)d_in[10];
  const float* gat_att = (const float*)d_in[11];
  const float* gat_bias= (const float*)d_in[12];
  const float* gat_ln_g= (const float*)d_in[13];
  const float* gat_ln_b= (const float*)d_in[14];
  const float* tr_Wq   = (const float*)d_in[15];
  const float* tr_bq   = (const float*)d_in[16];
  const float* tr_Wk   = (const float*)d_in[17];
  const float* tr_bk   = (const float*)d_in[18];
  const float* tr_Wv   = (const float*)d_in[19];
  const float* tr_bv   = (const float*)d_in[20];
  const float* tr_Wsk  = (const float*)d_in[21];
  const float* tr_bsk  = (const float*)d_in[22];
  const float* tr_ln_g = (const float*)d_in[23];
  const float* tr_ln_b = (const float*)d_in[24];
  const float* out_W   = (const float*)d_in[25];
  const float* out_b   = (const float*)d_in[26];
  const float* out_ln_g= (const float*)d_in[27];
  const float* out_ln_b= (const float*)d_in[28];

  // ---- workspace (256B-aligned) ----
  char* w = (char*)d_ws;
  auto take = [&](size_t bytes) -> char* {
    char* p = w;
    w += (bytes + 255) & ~(size_t)255;
    return p;
  };
  const size_t NB = (size_t)N_NODES * HID * sizeof(float);
  float* h    = (float*)take(NB);
  float* aggO = (float*)take(NB);
  unsigned short* hb  = (unsigned short*)take((size_t)N_NODES * HID * 2);
  unsigned short* xq  = (unsigned short*)take((size_t)N_NODES * 768 * 2);
  unsigned short* wbuf= (unsigned short*)take((size_t)(14 * 65536 + 262144) * 2);
  float* bcat = (float*)take(3328 * sizeof(float));
  int* indptr = (int*)take((N_NODES + 1) * sizeof(int));
  int* cursor = (int*)take(N_NODES * sizeof(int));
  int* counts = (int*)take(N_NODES * sizeof(int));
  int* esrc   = (int*)take(N_EDGES * sizeof(int));
  int* bsums  = (int*)take(64 * sizeof(int));
  unsigned short* skipb = (unsigned short*)aggO;
  char* w2 = (char*)xq;  // pool/out scratch overlays xq (free after tr_agg)
  auto take2 = [&](size_t bytes) -> char* {
    char* p = w2;
    w2 += (bytes + 255) & ~(size_t)255;
    return p;
  };
  unsigned short* geb = (unsigned short*)take2((size_t)N_GRAPH * 512 * 2);
  float* tbuf = (float*)take2((size_t)N_GRAPH * 512 * sizeof(float));

  const int EB = (N_EDGES + 255) / 256;
  const int WB = (N_NODES + 3) / 4;
  const int WB2 = N_NODES / 2;
  const int NSB = (N_NODES + 1023) / 1024;

  // --- weight/bias prep ---
  {
    dim3 g(8, 8, 14);
    prep_w<<<g, 256, 0, stream>>>(gat_Wl, gat_Wr, tr_Wq, tr_Wk, tr_Wv, tr_Wsk, wbuf);
    dim3 g2(16, 16);
    prep_wout<<<g2, 256, 0, stream>>>(out_W, wbuf + (size_t)14 * 65536);
    prep_bias<<<13, 256, 0, stream>>>(gat_bl, gat_br, tr_bq, tr_bk, tr_bv, bcat);
  }

  // --- CSR (dst-sorted) ---
  hipMemsetAsync(counts, 0, N_NODES * sizeof(int), stream);
  edge_count<<<EB, 256, 0, stream>>>(ei, counts);
  scan1<<<NSB, 1024, 0, stream>>>(counts, indptr, bsums, N_NODES);
  scan3<<<(N_NODES + 255) / 256, 256, 0, stream>>>(bsums, indptr, cursor, N_NODES);
  edge_scatter<<<EB, 256, 0, stream>>>(ei, cursor, esrc);

  // --- input embed ---
  {
    dim3 grid(HID / 64, (N_NODES + 63) / 64);
    gemm_bias<<<grid, 256, 0, stream>>>(x, in_W, in_b, aggO, N_NODES, HID, F_INPUT);
  }
  ln_act<<<WB, 256, 0, stream>>>(aggO, in_ln_g, in_ln_b, h, hb, N_NODES, HID, 1);

  // --- 5 GATv2 layers ---
  for (int l = 0; l < NLAYER; ++l) {
    mfma_launch(hb, wbuf + (size_t)(2 * l) * 65536, bcat + l * 512, xq,
                N_NODES, 512, HID, 2, stream);
    gat_agg<<<WB, 256, 0, stream>>>(xq, gat_att + l * HID, indptr, esrc,
                                    gat_bias + l * HID, gat_ln_g + l * HID,
                                    gat_ln_b + l * HID, h, hb);
  }

  // --- TransformerConv (qkv GEMM writes interleaved-kv layout via permuted W) ---
  mfma_launch(hb, wbuf + (size_t)13 * 65536, tr_bsk, skipb,
              N_NODES, HID, HID, 2, stream);
  mfma_launch(hb, wbuf + (size_t)10 * 65536, bcat + 2560, xq,
              N_NODES, 768, HID, 2, stream);
  tr_agg<<<WB2, 256, 0, stream>>>(xq, indptr, esrc, skipb, tr_ln_g, tr_ln_b, h);

  // --- pooling -> geb bf16 ---
  pool_seg<<<N_GRAPH, 256, 0, stream>>>(h, batch, geb);

  // --- output proj (MFMA) + final LN/GELU ---
  mfma_launch(geb, wbuf + (size_t)14 * 65536, out_b, tbuf,
              N_GRAPH, 512, 512, 0, stream);
  ln_act<<<(N_GRAPH + 3) / 4, 256, 0, stream>>>(tbuf, out_ln_g, out_ln_b,
                                                (float*)d_out, nullptr,
                                                N_GRAPH, 512, 1);
}